// Round 21
// baseline (1257.523 us; speedup 1.0000x reference)
//
#include <hip/hip_runtime.h>
#include <math.h>

#define N_NODES 10000
#define D_IN    512
#define D_H1    512
#define D_H2    256
#define N_EDGE  320000
#define NK      31
#define NSLICE  8
#define CAP     176
#define CAPP    177
#define TRIG    64

typedef short bf16x8 __attribute__((ext_vector_type(8)));
typedef float f32x4  __attribute__((ext_vector_type(4)));

static __device__ __forceinline__ ushort f2bf(float x) {
    uint u = __float_as_uint(x);
    uint r = (u + 0x7fffu + ((u >> 16) & 1u)) >> 16;
    return (ushort)r;
}
static __device__ __forceinline__ float bf2f(ushort h) {
    return __uint_as_float(((uint)h) << 16);
}

// ---------------------------------------------------------------------------
// f32 -> bf16 elementwise (4 elems/thread)
// ---------------------------------------------------------------------------
__global__ __launch_bounds__(256) void tobf16_plain(
    const float* __restrict__ F, ushort* __restrict__ H, int nquads)
{
    int q = blockIdx.x * 256 + threadIdx.x;
    if (q >= nquads) return;
    float4 v = *(const float4*)(F + (size_t)q * 4);
    *(ushort4*)(H + (size_t)q * 4) =
        make_ushort4(f2bf(v.x), f2bf(v.y), f2bf(v.z), f2bf(v.w));
}

// ---------------------------------------------------------------------------
// W [K,N] f32 -> Bt [N,K] bf16 (transpose + cast)
// ---------------------------------------------------------------------------
__global__ __launch_bounds__(256) void tobf16_transpose(
    const float* __restrict__ W, int K, int N, ushort* __restrict__ Bh)
{
    int q = blockIdx.x * 256 + threadIdx.x;
    int kq4 = K >> 2;
    if (q >= N * kq4) return;
    int nrow = q / kq4, kq = q - nrow * kq4;
    ushort h[4];
    #pragma unroll
    for (int j = 0; j < 4; ++j)
        h[j] = f2bf(W[(size_t)(kq * 4 + j) * N + nrow]);
    *(ushort4*)(Bh + (size_t)nrow * K + kq * 4) = make_ushort4(h[0], h[1], h[2], h[3]);
}

// ---------------------------------------------------------------------------
// MFMA GEMM (single-term bf16): C[M,N] = act(A @ Bt^T + bias).
// mode 1: relu, write bf16. mode 0: write f32 C + bf16 Cbf.
// ---------------------------------------------------------------------------
__global__ __launch_bounds__(256) void gemm_mfma(
    const ushort* __restrict__ A, const ushort* __restrict__ Bt,
    const float* __restrict__ bias, int M, int N, int K, int mode,
    float* __restrict__ C, ushort* __restrict__ Cbf, ushort* __restrict__ Cb16)
{
    const int i0 = blockIdx.x * 32, jb = blockIdx.y * 128;
    const int tid = threadIdx.x, w = tid >> 6, lane = tid & 63;
    const int l15 = lane & 15, l4 = lane >> 4;
    const int ir0 = min(i0 + l15, M - 1), ir1 = min(i0 + 16 + l15, M - 1);
    const int jc = jb + w * 32 + l15;

    const ushort* a0 = A + (size_t)ir0 * K + l4 * 8;
    const ushort* a1 = A + (size_t)ir1 * K + l4 * 8;
    const ushort* b0 = Bt + (size_t)jc * K + l4 * 8;
    const ushort* b1 = Bt + (size_t)(jc + 16) * K + l4 * 8;

    f32x4 acc00 = {0.f, 0.f, 0.f, 0.f};
    f32x4 acc01 = acc00, acc10 = acc00, acc11 = acc00;

    for (int k0 = 0; k0 < K; k0 += 32) {
        bf16x8 A0 = *(const bf16x8*)(a0 + k0);
        bf16x8 A1 = *(const bf16x8*)(a1 + k0);
        bf16x8 B0 = *(const bf16x8*)(b0 + k0);
        bf16x8 B1 = *(const bf16x8*)(b1 + k0);
        acc00 = __builtin_amdgcn_mfma_f32_16x16x32_bf16(A0, B0, acc00, 0, 0, 0);
        acc10 = __builtin_amdgcn_mfma_f32_16x16x32_bf16(A1, B0, acc10, 0, 0, 0);
        acc01 = __builtin_amdgcn_mfma_f32_16x16x32_bf16(A0, B1, acc01, 0, 0, 0);
        acc11 = __builtin_amdgcn_mfma_f32_16x16x32_bf16(A1, B1, acc11, 0, 0, 0);
    }

    float bs0 = bias[jc], bs1 = bias[jc + 16];
    #pragma unroll
    for (int rt = 0; rt < 2; ++rt) {
        #pragma unroll
        for (int q = 0; q < 4; ++q) {
            int i = i0 + rt * 16 + l4 * 4 + q;
            if (i >= M) continue;
            float v0 = (rt ? acc10[q] : acc00[q]) + bs0;
            float v1 = (rt ? acc11[q] : acc01[q]) + bs1;
            if (mode == 1) {
                v0 = fmaxf(v0, 0.f); v1 = fmaxf(v1, 0.f);
                Cb16[(size_t)i * N + jc]      = f2bf(v0);
                Cb16[(size_t)i * N + jc + 16] = f2bf(v1);
            } else {
                C[(size_t)i * N + jc]        = v0;
                C[(size_t)i * N + jc + 16]   = v1;
                Cbf[(size_t)i * N + jc]      = f2bf(v0);
                Cbf[(size_t)i * N + jc + 16] = f2bf(v1);
            }
        }
    }
}

// ---------------------------------------------------------------------------
// CSR build helpers
// ---------------------------------------------------------------------------
__global__ void hist_kernel(const int* __restrict__ idx, int* __restrict__ cnt, int n)
{
    int i = blockIdx.x * 256 + threadIdx.x;
    if (i < n) atomicAdd(&cnt[idx[i]], 1);
}

__global__ __launch_bounds__(256) void scan_kernel(
    const int* __restrict__ cnt, int* __restrict__ offs, int* __restrict__ nxt, int n)
{
    __shared__ int ssum[256];
    int t = threadIdx.x;
    int per = (n + 255) >> 8;
    int lo = t * per, hi = min(lo + per, n);
    int s = 0;
    for (int i = lo; i < hi; ++i) s += cnt[i];
    ssum[t] = s;
    __syncthreads();
    if (t == 0) {
        int run = 0;
        for (int i = 0; i < 256; ++i) { int x = ssum[i]; ssum[i] = run; run += x; }
    }
    __syncthreads();
    int run = ssum[t];
    for (int i = lo; i < hi; ++i) { offs[i] = run; nxt[i] = run; run += cnt[i]; }
}

__global__ void scatter_adj(const int* __restrict__ rows, const int* __restrict__ cols,
                            const float* __restrict__ vals, int* __restrict__ nxt,
                            int* __restrict__ ccol, float* __restrict__ cval, int n)
{
    int e = blockIdx.x * 256 + threadIdx.x;
    if (e >= n) return;
    int p = atomicAdd(&nxt[rows[e]], 1);
    ccol[p] = cols[e];
    cval[p] = vals[e];
}

__global__ void scatter_knn(const int* __restrict__ tc, int* __restrict__ nxt,
                            int* __restrict__ eid, int n)
{
    int e = blockIdx.x * 256 + threadIdx.x;
    if (e >= n) return;
    int p = atomicAdd(&nxt[tc[e]], 1);
    eid[p] = e;
}

// ---------------------------------------------------------------------------
// CSR spmm over bf16 H + FUSED row L2-normalize: writes xhi (normalized bf16)
// and hab (raw bf16) directly.
// ---------------------------------------------------------------------------
__global__ __launch_bounds__(256) void spmm_norm(
    const int* __restrict__ offs, const int* __restrict__ cnt,
    const int* __restrict__ cols, const float* __restrict__ vals,
    const ushort* __restrict__ Hb, ushort* __restrict__ xhi,
    ushort* __restrict__ hab, int n)
{
    int row = blockIdx.x * 4 + (threadIdx.x >> 6);
    if (row >= n) return;
    int lane = threadIdx.x & 63;
    int st = offs[row], m = cnt[row];
    float a0 = 0.f, a1 = 0.f, a2 = 0.f, a3 = 0.f;
    for (int p0 = 0; p0 < m; p0 += 16) {
        int c[16]; float v[16];
        #pragma unroll
        for (int jj = 0; jj < 16; ++jj) {
            int p = p0 + jj;
            bool ok = p < m;
            c[jj] = ok ? cols[st + p] : 0;
            v[jj] = ok ? vals[st + p] : 0.f;
        }
        ushort4 hv[16];
        #pragma unroll
        for (int jj = 0; jj < 16; ++jj)
            hv[jj] = *(const ushort4*)(Hb + (size_t)c[jj] * D_H2 + (lane << 2));
        #pragma unroll
        for (int jj = 0; jj < 16; ++jj) {
            a0 = fmaf(v[jj], bf2f(hv[jj].x), a0);
            a1 = fmaf(v[jj], bf2f(hv[jj].y), a1);
            a2 = fmaf(v[jj], bf2f(hv[jj].z), a2);
            a3 = fmaf(v[jj], bf2f(hv[jj].w), a3);
        }
    }
    *(ushort4*)(hab + (size_t)row * D_H2 + (lane << 2)) =
        make_ushort4(f2bf(a0), f2bf(a1), f2bf(a2), f2bf(a3));
    float s = a0 * a0 + a1 * a1 + a2 * a2 + a3 * a3;
    #pragma unroll
    for (int mm = 1; mm < 64; mm <<= 1) s += __shfl_xor(s, mm);
    float inv = 1.f / fmaxf(sqrtf(s), 1e-12f);
    *(ushort4*)(xhi + (size_t)row * D_H2 + (lane << 2)) =
        make_ushort4(f2bf(a0 * inv), f2bf(a1 * inv),
                     f2bf(a2 * inv), f2bf(a3 * inv));
}

// ---------------------------------------------------------------------------
// Wave-parallel top-31 compaction (bisection over monotone uint codes).
// cols stored as ushort (N < 65536). CAP = 176 <= 3 x 64 lanes.
// exact=false: early-exit once count(>=piv) <= 48, keep ALL of them.
// exact=true: full bisection, tie-fill to exactly NK.
// ---------------------------------------------------------------------------
__device__ __forceinline__ void compact_row(
    float (*bufv)[CAPP], ushort (*bufc)[CAPP], int* bcnt, float* thr, int* cpos,
    int r, int lane, bool exact)
{
    int m = min(bcnt[r], CAP);
    float ev0 = 0.f, ev1 = 0.f, ev2 = 0.f;
    ushort ec0 = 0, ec1 = 0, ec2 = 0;
    uint  ue0 = 0u, ue1 = 0u, ue2 = 0u;
    if (lane < m)       { ev0 = bufv[r][lane];       ec0 = bufc[r][lane];       uint u = __float_as_uint(ev0); ue0 = (u >> 31) ? ~u : (u | 0x80000000u); }
    if (lane + 64 < m)  { ev1 = bufv[r][lane + 64];  ec1 = bufc[r][lane + 64];  uint u = __float_as_uint(ev1); ue1 = (u >> 31) ? ~u : (u | 0x80000000u); }
    if (lane + 128 < m) { ev2 = bufv[r][lane + 128]; ec2 = bufc[r][lane + 128]; uint u = __float_as_uint(ev2); ue2 = (u >> 31) ? ~u : (u | 0x80000000u); }

    uint piv = 0u;
    int  cnt = m;
    for (int bit = 31; bit >= 0; --bit) {
        uint c = piv | (1u << bit);
        int k = __popcll(__ballot(ue0 >= c)) + __popcll(__ballot(ue1 >= c))
              + __popcll(__ballot(ue2 >= c));
        if (k >= NK) {
            piv = c; cnt = k;
            if (!exact && cnt <= 48) break;
        }
    }
    if (lane == 0) cpos[r] = 0;
    // same-wave LDS program order: atomics below see the reset
    if (!exact && cnt <= 48) {
        if (lane < m       && ue0 >= piv) { int p = atomicAdd(&cpos[r], 1); bufv[r][p] = ev0; bufc[r][p] = ec0; }
        if (lane + 64 < m  && ue1 >= piv) { int p = atomicAdd(&cpos[r], 1); bufv[r][p] = ev1; bufc[r][p] = ec1; }
        if (lane + 128 < m && ue2 >= piv) { int p = atomicAdd(&cpos[r], 1); bufv[r][p] = ev2; bufc[r][p] = ec2; }
        if (lane == 0) {
            bcnt[r] = cnt;
            thr[r] = (piv & 0x80000000u) ? __uint_as_float(piv ^ 0x80000000u)
                                         : __uint_as_float(~piv);
        }
    } else {
        if (ue0 > piv) { int p = atomicAdd(&cpos[r], 1); bufv[r][p] = ev0; bufc[r][p] = ec0; }
        if (ue1 > piv) { int p = atomicAdd(&cpos[r], 1); bufv[r][p] = ev1; bufc[r][p] = ec1; }
        if (ue2 > piv) { int p = atomicAdd(&cpos[r], 1); bufv[r][p] = ev2; bufc[r][p] = ec2; }
        if (ue0 == piv) { int p = atomicAdd(&cpos[r], 1); if (p < NK) { bufv[r][p] = ev0; bufc[r][p] = ec0; } }
        if (ue1 == piv) { int p = atomicAdd(&cpos[r], 1); if (p < NK) { bufv[r][p] = ev1; bufc[r][p] = ec1; } }
        if (ue2 == piv) { int p = atomicAdd(&cpos[r], 1); if (p < NK) { bufv[r][p] = ev2; bufc[r][p] = ec2; } }
        if (lane == 0) {
            bcnt[r] = NK;
            thr[r] = (piv & 0x80000000u) ? __uint_as_float(piv ^ 0x80000000u)
                                         : __uint_as_float(~piv);
        }
    }
}

// ---------------------------------------------------------------------------
// Fused sim-GEMM (single-term bf16 MFMA) + filtered top-31 collection.
// 16 rows/block, 128 cols per BARRIER ROUND (two sequential 64-col
// sub-chunks, no barrier between): barrier rounds 20 -> 10 with TRIG HELD
// at 64 (R14's confound removed). Invariant: post-compact <= 48 + 128
// pushes <= 176 = CAP. LDS ~17.2 KB, occupancy stays at waves_per_eu cap.
// ---------------------------------------------------------------------------
__global__ __launch_bounds__(256, 6) void simtopk(
    const ushort* __restrict__ Xhi,
    float* __restrict__ ptv, int* __restrict__ ptc, int n)
{
    __shared__ float  bufv[16][CAPP];
    __shared__ ushort bufc[16][CAPP];
    __shared__ int   bcnt[16];
    __shared__ float thr[16];
    __shared__ int   cpos[16];

    const int slice = blockIdx.x & 7;
    const int i0 = (blockIdx.x >> 3) * 16;
    const int jspan = n / NSLICE;                 // 1250
    const int jbeg = slice * jspan, jend = jbeg + jspan;
    const int tid = threadIdx.x;
    const int w = tid >> 6, lane = tid & 63;
    const int l15 = lane & 15, l4 = lane >> 4;

    // A: 16 rows x K=256 -> 32 VGPRs
    bf16x8 Ahi[8];
    {
        int ir = min(i0 + l15, n - 1);
        const ushort* ph = Xhi + (size_t)ir * D_H2 + l4 * 8;
        #pragma unroll
        for (int ks = 0; ks < 8; ++ks)
            Ahi[ks] = *(const bf16x8*)(ph + ks * 32);
    }

    if (tid < 16) { thr[tid] = -1e30f; bcnt[tid] = 0; }
    __syncthreads();

    float tregs[4];
    #pragma unroll
    for (int q = 0; q < 4; ++q) tregs[q] = thr[l4 * 4 + q];

    for (int j0 = jbeg; j0 < jend; j0 += 128) {
        // ---- sub-chunk A: cols j0 .. j0+63 ----
        {
            f32x4 acc = {0.f, 0.f, 0.f, 0.f};
            const int jc = j0 + w * 16 + l15;
            const size_t b0 = (size_t)min(jc, n - 1) * D_H2 + l4 * 8;
            bf16x8 bh[8];
            #pragma unroll
            for (int ks = 0; ks < 8; ++ks)
                bh[ks] = *(const bf16x8*)(Xhi + b0 + ks * 32);
            #pragma unroll
            for (int ks = 0; ks < 8; ++ks)
                acc = __builtin_amdgcn_mfma_f32_16x16x32_bf16(Ahi[ks], bh[ks], acc, 0, 0, 0);
            #pragma unroll
            for (int q = 0; q < 4; ++q) {
                int r = l4 * 4 + q;
                if (acc[q] > tregs[q] && jc < jend) {
                    int p = atomicAdd(&bcnt[r], 1);
                    if (p < CAP) { bufv[r][p] = acc[q]; bufc[r][p] = (ushort)jc; }
                }
            }
        }
        // ---- sub-chunk B: cols j0+64 .. j0+127 (no barrier between) ----
        {
            f32x4 acc = {0.f, 0.f, 0.f, 0.f};
            const int jc = j0 + 64 + w * 16 + l15;
            const size_t b0 = (size_t)min(jc, n - 1) * D_H2 + l4 * 8;
            bf16x8 bh[8];
            #pragma unroll
            for (int ks = 0; ks < 8; ++ks)
                bh[ks] = *(const bf16x8*)(Xhi + b0 + ks * 32);
            #pragma unroll
            for (int ks = 0; ks < 8; ++ks)
                acc = __builtin_amdgcn_mfma_f32_16x16x32_bf16(Ahi[ks], bh[ks], acc, 0, 0, 0);
            #pragma unroll
            for (int q = 0; q < 4; ++q) {
                int r = l4 * 4 + q;
                if (acc[q] > tregs[q] && jc < jend) {
                    int p = atomicAdd(&bcnt[r], 1);
                    if (p < CAP) { bufv[r][p] = acc[q]; bufc[r][p] = (ushort)jc; }
                }
            }
        }
        __syncthreads();

        // compaction: wave w owns rows w*4..w*4+3
        #pragma unroll
        for (int rr = 0; rr < 4; ++rr) {
            int r = w * 4 + rr;
            if (bcnt[r] > TRIG) compact_row(bufv, bufc, bcnt, thr, cpos, r, lane, false);
        }
        __syncthreads();

        #pragma unroll
        for (int q = 0; q < 4; ++q) tregs[q] = thr[l4 * 4 + q];
    }

    // final exact compaction
    #pragma unroll
    for (int rr = 0; rr < 4; ++rr) {
        int r = w * 4 + rr;
        if (bcnt[r] > NK) compact_row(bufv, bufc, bcnt, thr, cpos, r, lane, true);
    }
    __syncthreads();

    for (int e = tid; e < 16 * NK; e += 256) {
        int r = e / NK, q = e - r * NK;
        if (i0 + r < n) {
            size_t o = ((size_t)slice * n + i0 + r) * NK + q;
            ptv[o] = bufv[r][q];
            ptc[o] = (int)bufc[r][q];
        }
    }
}

// ---------------------------------------------------------------------------
// Merge 8 partial top-31 lists -> final top-31 (one wave per row, 248 cands)
// ---------------------------------------------------------------------------
__global__ __launch_bounds__(256) void mergetop(
    const float* __restrict__ pv, const int* __restrict__ pc,
    float* __restrict__ tv, int* __restrict__ tc, int n)
{
    int row = blockIdx.x * 4 + (threadIdx.x >> 6);
    if (row >= n) return;
    int lane = threadIdx.x & 63;
    const int TOT = NSLICE * NK;  // 248
    float v0 = -1e30f, v1 = -1e30f, v2 = -1e30f, v3 = -1e30f;
    int c0 = 0, c1 = 0, c2 = 0, c3 = 0;
    #pragma unroll
    for (int qq = 0; qq < 4; ++qq) {
        int e = lane + qq * 64;
        if (e < TOT) {
            int s = e / NK, q = e - s * NK;
            size_t o = ((size_t)s * n + row) * NK + q;
            float vv = pv[o]; int cc = pc[o];
            if (qq == 0) { v0 = vv; c0 = cc; }
            else if (qq == 1) { v1 = vv; c1 = cc; }
            else if (qq == 2) { v2 = vv; c2 = cc; }
            else { v3 = vv; c3 = cc; }
        }
    }
    for (int t = 0; t < NK; ++t) {
        float m = v0; int sel = 0;
        if (v1 > m) { m = v1; sel = 1; }
        if (v2 > m) { m = v2; sel = 2; }
        if (v3 > m) { m = v3; sel = 3; }
        float bm = m;
        int bid = (lane << 2) | sel;
        #pragma unroll
        for (int off = 1; off < 64; off <<= 1) {
            float om = __shfl_xor(bm, off);
            int oid = __shfl_xor(bid, off);
            if (om > bm || (om == bm && oid < bid)) { bm = om; bid = oid; }
        }
        int wl = bid >> 2, slot = bid & 3;
        int wcol = (slot == 0) ? c0 : (slot == 1) ? c1 : (slot == 2) ? c2 : c3;
        int wc = __shfl(wcol, wl);
        if (lane == 0) { tv[(size_t)row * NK + t] = bm; tc[(size_t)row * NK + t] = wc; }
        if (lane == wl) {
            if (slot == 0) v0 = -1e30f;
            else if (slot == 1) v1 = -1e30f;
            else if (slot == 2) v2 = -1e30f;
            else v3 = -1e30f;
        }
    }
}

// ---------------------------------------------------------------------------
// Edge-parallel norm accumulation (hub-skew safe)
// ---------------------------------------------------------------------------
__global__ void knorm_edges(const float* __restrict__ tv, const int* __restrict__ tc,
                            float* __restrict__ nrm, int nedge)
{
    int e = blockIdx.x * 256 + threadIdx.x;
    if (e >= nedge) return;
    float v = tv[e];
    atomicAdd(&nrm[e / NK], v);
    atomicAdd(&nrm[tc[e]], v);
}

__global__ void knorm_fin(const float* __restrict__ nrm, float* __restrict__ rn, int n)
{
    int i = blockIdx.x * 256 + threadIdx.x;
    if (i < n) rn[i] = rsqrtf(nrm[i]);
}

// ---------------------------------------------------------------------------
// wk[e] = max(tv[e]*rn[row]*rn[col], 0) * (1-t)
// ---------------------------------------------------------------------------
__global__ void knn_weights(const float* __restrict__ tv, const int* __restrict__ tc,
                            const float* __restrict__ rn, const float* __restrict__ tptr,
                            float* __restrict__ wk, int nedge)
{
    int e = blockIdx.x * 256 + threadIdx.x;
    if (e >= nedge) return;
    int row = e / NK;
    int col = tc[e];
    wk[e] = fmaxf(tv[e] * rn[row] * rn[col], 0.f) * (1.f - *tptr);
}

// ---------------------------------------------------------------------------
// rev_prep: flatten rev-CSR indirection for hp phase B
// ---------------------------------------------------------------------------
__global__ void rev_prep(const int* __restrict__ eid2, const float* __restrict__ wk,
                         int* __restrict__ srcrev, float* __restrict__ wkrev, int n)
{
    int p = blockIdx.x * 256 + threadIdx.x;
    if (p >= n) return;
    int e = eid2[p];
    srcrev[p] = e / NK;
    wkrev[p] = wk[e];
}

// ---------------------------------------------------------------------------
// h_p[row] = [fwd knn + rev knn] + t*[adj], batched gathers (16 deep)
// ---------------------------------------------------------------------------
__global__ __launch_bounds__(256) void hp_kernel(
    const int* __restrict__ tc, const float* __restrict__ wk,
    const int* __restrict__ offs2, const int* __restrict__ cnt2,
    const int* __restrict__ srcrev, const float* __restrict__ wkrev,
    const ushort* __restrict__ hab,
    const int* __restrict__ aoffs, const int* __restrict__ acnt,
    const int* __restrict__ acol, const float* __restrict__ aval,
    const float* __restrict__ tptr, float* __restrict__ hp, int n)
{
    int row = blockIdx.x * 4 + (threadIdx.x >> 6);
    if (row >= n) return;
    int lane = threadIdx.x & 63;
    float t = *tptr;
    float a0 = 0.f, a1 = 0.f, a2 = 0.f, a3 = 0.f;

    // Phase A: fwd knn edges
    {
        const int base = row * NK;
        for (int j0 = 0; j0 < NK; j0 += 16) {
            int c[16]; float w[16];
            #pragma unroll
            for (int jj = 0; jj < 16; ++jj) {
                int j = j0 + jj;
                bool ok = j < NK;
                c[jj] = ok ? tc[base + j] : 0;
                w[jj] = ok ? wk[base + j] : 0.f;
            }
            ushort4 hv[16];
            #pragma unroll
            for (int jj = 0; jj < 16; ++jj)
                hv[jj] = *(const ushort4*)(hab + (size_t)c[jj] * D_H2 + (lane << 2));
            #pragma unroll
            for (int jj = 0; jj < 16; ++jj) {
                a0 = fmaf(w[jj], bf2f(hv[jj].x), a0);
                a1 = fmaf(w[jj], bf2f(hv[jj].y), a1);
                a2 = fmaf(w[jj], bf2f(hv[jj].z), a2);
                a3 = fmaf(w[jj], bf2f(hv[jj].w), a3);
            }
        }
    }
    // Phase B: rev knn edges (affine srcrev/wkrev)
    {
        int st = offs2[row], m = cnt2[row];
        for (int p0 = 0; p0 < m; p0 += 16) {
            int c[16]; float w[16];
            #pragma unroll
            for (int jj = 0; jj < 16; ++jj) {
                int p = p0 + jj;
                bool ok = p < m;
                c[jj] = ok ? srcrev[st + p] : 0;
                w[jj] = ok ? wkrev[st + p] : 0.f;
            }
            ushort4 hv[16];
            #pragma unroll
            for (int jj = 0; jj < 16; ++jj)
                hv[jj] = *(const ushort4*)(hab + (size_t)c[jj] * D_H2 + (lane << 2));
            #pragma unroll
            for (int jj = 0; jj < 16; ++jj) {
                a0 = fmaf(w[jj], bf2f(hv[jj].x), a0);
                a1 = fmaf(w[jj], bf2f(hv[jj].y), a1);
                a2 = fmaf(w[jj], bf2f(hv[jj].z), a2);
                a3 = fmaf(w[jj], bf2f(hv[jj].w), a3);
            }
        }
    }
    // Phase C: original adj edges, scaled by t
    {
        int st = aoffs[row], m = acnt[row];
        for (int p0 = 0; p0 < m; p0 += 16) {
            int c[16]; float w[16];
            #pragma unroll
            for (int jj = 0; jj < 16; ++jj) {
                int p = p0 + jj;
                bool ok = p < m;
                c[jj] = ok ? acol[st + p] : 0;
                w[jj] = ok ? aval[st + p] * t : 0.f;
            }
            ushort4 hv[16];
            #pragma unroll
            for (int jj = 0; jj < 16; ++jj)
                hv[jj] = *(const ushort4*)(hab + (size_t)c[jj] * D_H2 + (lane << 2));
            #pragma unroll
            for (int jj = 0; jj < 16; ++jj) {
                a0 = fmaf(w[jj], bf2f(hv[jj].x), a0);
                a1 = fmaf(w[jj], bf2f(hv[jj].y), a1);
                a2 = fmaf(w[jj], bf2f(hv[jj].z), a2);
                a3 = fmaf(w[jj], bf2f(hv[jj].w), a3);
            }
        }
    }
    *(float4*)(hp + (size_t)row * D_H2 + (lane << 2)) = make_float4(a0, a1, a2, a3);
}

// ---------------------------------------------------------------------------
extern "C" void kernel_launch(void* const* d_in, const int* in_sizes, int n_in,
                              void* d_out, int out_size, void* d_ws, size_t ws_size,
                              hipStream_t stream)
{
    const float* feature = (const float*)d_in[0];
    const int*   arows   = (const int*)d_in[1];
    const int*   acols   = (const int*)d_in[2];
    const float* avals   = (const float*)d_in[3];
    const float* W1      = (const float*)d_in[4];
    const float* b1      = (const float*)d_in[5];
    const float* W2      = (const float*)d_in[6];
    const float* b2      = (const float*)d_in[7];
    const float* tptr    = (const float*)d_in[8];

    float* hs = (float*)d_out;                            // [N, 256]
    float* hp = (float*)d_out + (size_t)N_NODES * D_H2;   // [N, 256]

    char* ws = (char*)d_ws;
    // R0 [0..10.24 MB): fb16 -> later xhi (dead after simtopk) -> wk
    ushort* fb16 = (ushort*)(ws + 0);            // [cast..gemm1]
    ushort* xhi  = (ushort*)(ws + 0);            // [spmm_norm..simtopk]
    float*  wk   = (float*) (ws + 0);            // [knn_weights..hp]
    ushort* hsb  = (ushort*)(ws + 10240000);     // 5.12 MB [gemm2..spmm_norm]
    float*  ptv  = (float*) (ws + 10240000);     // 9.92 MB [simtopk..mergetop]
    int*    srcrev = (int*) (ws + 10240000);     // [rev_prep..hp] (ptv dead)
    float*  wkrev  = (float*)(ws + 11480000);    // [rev_prep..hp]
    // R1 [20.48..40.96 MB): h1b16 -> later ptc / hab
    ushort* h1b16 = (ushort*)(ws + 20480000);    // 10.24 MB [gemm1..gemm2]
    int*    ptc   = (int*)   (ws + 20480000);    // 9.92 MB [simtopk..mergetop]
    ushort* hab   = (ushort*)(ws + 30720000);    // 5.12 MB [spmm_norm..hp]
    // R2 small persistent
    float*  tv    = (float*)(ws + 40960000);     // 1,240,000 B
    int*    tc    = (int*)  (ws + 42200000);     // 1,240,000 B
    float*  rn    = (float*)(ws + 43440000);     // 40,000 B
    int*    cnt1  = (int*)  (ws + 43480000);
    int*    offs1 = (int*)  (ws + 43520000);
    int*    next1 = (int*)  (ws + 43560000);
    int*    ccol1 = (int*)  (ws + 43600000);     // 1,280,000 B
    float*  cval1 = (float*)(ws + 44880000);     // 1,280,000 B
    int*    cnt2  = (int*)  (ws + 46160000);
    int*    offs2 = (int*)  (ws + 46200000);
    int*    next2 = (int*)  (ws + 46240000);
    int*    eid2  = (int*)  (ws + 46280000);     // 1,240,000 B
    ushort* w1t   = (ushort*)(ws + 47520000);    // 524,288 B
    ushort* w2t   = (ushort*)(ws + 48044288);    // 262,144 B
    float*  nrm   = (float*)(ws + 48306432);     // 40,000 B -> 48,346,432 total

    hipMemsetAsync(cnt1, 0, N_NODES * sizeof(int), stream);
    hipMemsetAsync(cnt2, 0, N_NODES * sizeof(int), stream);
    hipMemsetAsync(nrm,  0, N_NODES * sizeof(float), stream);

    // bf16 casts
    tobf16_plain<<<(N_NODES * D_IN / 4 + 255) / 256, 256, 0, stream>>>(
        feature, fb16, N_NODES * D_IN / 4);
    tobf16_transpose<<<(D_H1 * D_IN / 4 + 255) / 256, 256, 0, stream>>>(
        W1, D_IN, D_H1, w1t);
    tobf16_transpose<<<(D_H2 * D_H1 / 4 + 255) / 256, 256, 0, stream>>>(
        W2, D_H1, D_H2, w2t);

    // MLP via single-term bf16 MFMA
    gemm_mfma<<<dim3((N_NODES + 31) / 32, D_H1 / 128), 256, 0, stream>>>(
        fb16, w1t, b1, N_NODES, D_H1, D_IN, 1, nullptr, nullptr, h1b16);
    gemm_mfma<<<dim3((N_NODES + 31) / 32, D_H2 / 128), 256, 0, stream>>>(
        h1b16, w2t, b2, N_NODES, D_H2, D_H1, 0, hs, hsb, nullptr);

    // adj CSR + fused spmm/rownorm -> xhi, hab
    hist_kernel<<<(N_EDGE + 255) / 256, 256, 0, stream>>>(arows, cnt1, N_EDGE);
    scan_kernel<<<1, 256, 0, stream>>>(cnt1, offs1, next1, N_NODES);
    scatter_adj<<<(N_EDGE + 255) / 256, 256, 0, stream>>>(
        arows, acols, avals, next1, ccol1, cval1, N_EDGE);
    spmm_norm<<<(N_NODES + 3) / 4, 256, 0, stream>>>(
        offs1, cnt1, ccol1, cval1, hsb, xhi, hab, N_NODES);

    // cosine sim + top-k (16-row blocks, 128-col barrier rounds)
    simtopk<<<((N_NODES + 15) / 16) * NSLICE, 256, 0, stream>>>(
        xhi, ptv, ptc, N_NODES);
    mergetop<<<(N_NODES + 3) / 4, 256, 0, stream>>>(ptv, ptc, tv, tc, N_NODES);

    // reverse CSR over knn entries
    hist_kernel<<<(N_NODES * NK + 255) / 256, 256, 0, stream>>>(tc, cnt2, N_NODES * NK);
    scan_kernel<<<1, 256, 0, stream>>>(cnt2, offs2, next2, N_NODES);
    scatter_knn<<<(N_NODES * NK + 255) / 256, 256, 0, stream>>>(
        tc, next2, eid2, N_NODES * NK);

    // degree norm (edge-parallel, hub-safe), weights, rev flatten, propagation
    knorm_edges<<<(N_NODES * NK + 255) / 256, 256, 0, stream>>>(
        tv, tc, nrm, N_NODES * NK);
    knorm_fin<<<(N_NODES + 255) / 256, 256, 0, stream>>>(nrm, rn, N_NODES);
    knn_weights<<<(N_NODES * NK + 255) / 256, 256, 0, stream>>>(
        tv, tc, rn, tptr, wk, N_NODES * NK);
    rev_prep<<<(N_NODES * NK + 255) / 256, 256, 0, stream>>>(
        eid2, wk, srcrev, wkrev, N_NODES * NK);
    hp_kernel<<<(N_NODES + 3) / 4, 256, 0, stream>>>(
        tc, wk, offs2, cnt2, srcrev, wkrev, hab, offs1, cnt1, ccol1, cval1,
        tptr, hp, N_NODES);
}

// Round 22
// 1231.524 us; speedup vs baseline: 1.0211x; 1.0211x over previous
//
#include <hip/hip_runtime.h>
#include <math.h>

#define N_NODES 10000
#define D_IN    512
#define D_H1    512
#define D_H2    256
#define N_EDGE  320000
#define NK      31
#define NSLICE  8
#define CAP     128
#define CAPP    129
#define TRIG    64

typedef short bf16x8 __attribute__((ext_vector_type(8)));
typedef float f32x4  __attribute__((ext_vector_type(4)));

static __device__ __forceinline__ ushort f2bf(float x) {
    uint u = __float_as_uint(x);
    uint r = (u + 0x7fffu + ((u >> 16) & 1u)) >> 16;
    return (ushort)r;
}
static __device__ __forceinline__ float bf2f(ushort h) {
    return __uint_as_float(((uint)h) << 16);
}

// ---------------------------------------------------------------------------
// f32 -> bf16 elementwise (4 elems/thread)
// ---------------------------------------------------------------------------
__global__ __launch_bounds__(256) void tobf16_plain(
    const float* __restrict__ F, ushort* __restrict__ H, int nquads)
{
    int q = blockIdx.x * 256 + threadIdx.x;
    if (q >= nquads) return;
    float4 v = *(const float4*)(F + (size_t)q * 4);
    *(ushort4*)(H + (size_t)q * 4) =
        make_ushort4(f2bf(v.x), f2bf(v.y), f2bf(v.z), f2bf(v.w));
}

// ---------------------------------------------------------------------------
// W [K,N] f32 -> Bt [N,K] bf16 (transpose + cast)
// ---------------------------------------------------------------------------
__global__ __launch_bounds__(256) void tobf16_transpose(
    const float* __restrict__ W, int K, int N, ushort* __restrict__ Bh)
{
    int q = blockIdx.x * 256 + threadIdx.x;
    int kq4 = K >> 2;
    if (q >= N * kq4) return;
    int nrow = q / kq4, kq = q - nrow * kq4;
    ushort h[4];
    #pragma unroll
    for (int j = 0; j < 4; ++j)
        h[j] = f2bf(W[(size_t)(kq * 4 + j) * N + nrow]);
    *(ushort4*)(Bh + (size_t)nrow * K + kq * 4) = make_ushort4(h[0], h[1], h[2], h[3]);
}

// ---------------------------------------------------------------------------
// MFMA GEMM (single-term bf16): C[M,N] = act(A @ Bt^T + bias).
// mode 1: relu, write bf16. mode 0: write f32 C + bf16 Cbf.
// ---------------------------------------------------------------------------
__global__ __launch_bounds__(256) void gemm_mfma(
    const ushort* __restrict__ A, const ushort* __restrict__ Bt,
    const float* __restrict__ bias, int M, int N, int K, int mode,
    float* __restrict__ C, ushort* __restrict__ Cbf, ushort* __restrict__ Cb16)
{
    const int i0 = blockIdx.x * 32, jb = blockIdx.y * 128;
    const int tid = threadIdx.x, w = tid >> 6, lane = tid & 63;
    const int l15 = lane & 15, l4 = lane >> 4;
    const int ir0 = min(i0 + l15, M - 1), ir1 = min(i0 + 16 + l15, M - 1);
    const int jc = jb + w * 32 + l15;

    const ushort* a0 = A + (size_t)ir0 * K + l4 * 8;
    const ushort* a1 = A + (size_t)ir1 * K + l4 * 8;
    const ushort* b0 = Bt + (size_t)jc * K + l4 * 8;
    const ushort* b1 = Bt + (size_t)(jc + 16) * K + l4 * 8;

    f32x4 acc00 = {0.f, 0.f, 0.f, 0.f};
    f32x4 acc01 = acc00, acc10 = acc00, acc11 = acc00;

    for (int k0 = 0; k0 < K; k0 += 32) {
        bf16x8 A0 = *(const bf16x8*)(a0 + k0);
        bf16x8 A1 = *(const bf16x8*)(a1 + k0);
        bf16x8 B0 = *(const bf16x8*)(b0 + k0);
        bf16x8 B1 = *(const bf16x8*)(b1 + k0);
        acc00 = __builtin_amdgcn_mfma_f32_16x16x32_bf16(A0, B0, acc00, 0, 0, 0);
        acc10 = __builtin_amdgcn_mfma_f32_16x16x32_bf16(A1, B0, acc10, 0, 0, 0);
        acc01 = __builtin_amdgcn_mfma_f32_16x16x32_bf16(A0, B1, acc01, 0, 0, 0);
        acc11 = __builtin_amdgcn_mfma_f32_16x16x32_bf16(A1, B1, acc11, 0, 0, 0);
    }

    float bs0 = bias[jc], bs1 = bias[jc + 16];
    #pragma unroll
    for (int rt = 0; rt < 2; ++rt) {
        #pragma unroll
        for (int q = 0; q < 4; ++q) {
            int i = i0 + rt * 16 + l4 * 4 + q;
            if (i >= M) continue;
            float v0 = (rt ? acc10[q] : acc00[q]) + bs0;
            float v1 = (rt ? acc11[q] : acc01[q]) + bs1;
            if (mode == 1) {
                v0 = fmaxf(v0, 0.f); v1 = fmaxf(v1, 0.f);
                Cb16[(size_t)i * N + jc]      = f2bf(v0);
                Cb16[(size_t)i * N + jc + 16] = f2bf(v1);
            } else {
                C[(size_t)i * N + jc]        = v0;
                C[(size_t)i * N + jc + 16]   = v1;
                Cbf[(size_t)i * N + jc]      = f2bf(v0);
                Cbf[(size_t)i * N + jc + 16] = f2bf(v1);
            }
        }
    }
}

// ---------------------------------------------------------------------------
// CSR build helpers
// ---------------------------------------------------------------------------
__global__ void hist_kernel(const int* __restrict__ idx, int* __restrict__ cnt, int n)
{
    int i = blockIdx.x * 256 + threadIdx.x;
    if (i < n) atomicAdd(&cnt[idx[i]], 1);
}

__global__ __launch_bounds__(256) void scan_kernel(
    const int* __restrict__ cnt, int* __restrict__ offs, int* __restrict__ nxt, int n)
{
    __shared__ int ssum[256];
    int t = threadIdx.x;
    int per = (n + 255) >> 8;
    int lo = t * per, hi = min(lo + per, n);
    int s = 0;
    for (int i = lo; i < hi; ++i) s += cnt[i];
    ssum[t] = s;
    __syncthreads();
    if (t == 0) {
        int run = 0;
        for (int i = 0; i < 256; ++i) { int x = ssum[i]; ssum[i] = run; run += x; }
    }
    __syncthreads();
    int run = ssum[t];
    for (int i = lo; i < hi; ++i) { offs[i] = run; nxt[i] = run; run += cnt[i]; }
}

__global__ void scatter_adj(const int* __restrict__ rows, const int* __restrict__ cols,
                            const float* __restrict__ vals, int* __restrict__ nxt,
                            int* __restrict__ ccol, float* __restrict__ cval, int n)
{
    int e = blockIdx.x * 256 + threadIdx.x;
    if (e >= n) return;
    int p = atomicAdd(&nxt[rows[e]], 1);
    ccol[p] = cols[e];
    cval[p] = vals[e];
}

__global__ void scatter_knn(const int* __restrict__ tc, int* __restrict__ nxt,
                            int* __restrict__ eid, int n)
{
    int e = blockIdx.x * 256 + threadIdx.x;
    if (e >= n) return;
    int p = atomicAdd(&nxt[tc[e]], 1);
    eid[p] = e;
}

// ---------------------------------------------------------------------------
// CSR spmm over bf16 H + FUSED row L2-normalize: writes xhi (normalized bf16)
// and hab (raw bf16) directly.
// ---------------------------------------------------------------------------
__global__ __launch_bounds__(256) void spmm_norm(
    const int* __restrict__ offs, const int* __restrict__ cnt,
    const int* __restrict__ cols, const float* __restrict__ vals,
    const ushort* __restrict__ Hb, ushort* __restrict__ xhi,
    ushort* __restrict__ hab, int n)
{
    int row = blockIdx.x * 4 + (threadIdx.x >> 6);
    if (row >= n) return;
    int lane = threadIdx.x & 63;
    int st = offs[row], m = cnt[row];
    float a0 = 0.f, a1 = 0.f, a2 = 0.f, a3 = 0.f;
    for (int p0 = 0; p0 < m; p0 += 16) {
        int c[16]; float v[16];
        #pragma unroll
        for (int jj = 0; jj < 16; ++jj) {
            int p = p0 + jj;
            bool ok = p < m;
            c[jj] = ok ? cols[st + p] : 0;
            v[jj] = ok ? vals[st + p] : 0.f;
        }
        ushort4 hv[16];
        #pragma unroll
        for (int jj = 0; jj < 16; ++jj)
            hv[jj] = *(const ushort4*)(Hb + (size_t)c[jj] * D_H2 + (lane << 2));
        #pragma unroll
        for (int jj = 0; jj < 16; ++jj) {
            a0 = fmaf(v[jj], bf2f(hv[jj].x), a0);
            a1 = fmaf(v[jj], bf2f(hv[jj].y), a1);
            a2 = fmaf(v[jj], bf2f(hv[jj].z), a2);
            a3 = fmaf(v[jj], bf2f(hv[jj].w), a3);
        }
    }
    *(ushort4*)(hab + (size_t)row * D_H2 + (lane << 2)) =
        make_ushort4(f2bf(a0), f2bf(a1), f2bf(a2), f2bf(a3));
    float s = a0 * a0 + a1 * a1 + a2 * a2 + a3 * a3;
    #pragma unroll
    for (int mm = 1; mm < 64; mm <<= 1) s += __shfl_xor(s, mm);
    float inv = 1.f / fmaxf(sqrtf(s), 1e-12f);
    *(ushort4*)(xhi + (size_t)row * D_H2 + (lane << 2)) =
        make_ushort4(f2bf(a0 * inv), f2bf(a1 * inv),
                     f2bf(a2 * inv), f2bf(a3 * inv));
}

// ---------------------------------------------------------------------------
// Wave-parallel top-31 compaction (bisection over monotone uint codes).
// cols stored as ushort (N < 65536). CAP = 128 = 2 x 64 lanes.
// ---------------------------------------------------------------------------
__device__ __forceinline__ void compact_row(
    float (*bufv)[CAPP], ushort (*bufc)[CAPP], int* bcnt, float* thr, int* cpos,
    int r, int lane, bool exact)
{
    int m = min(bcnt[r], CAP);
    float ev0 = 0.f, ev1 = 0.f;
    ushort ec0 = 0, ec1 = 0;
    uint  ue0 = 0u, ue1 = 0u;
    if (lane < m)      { ev0 = bufv[r][lane];      ec0 = bufc[r][lane];      uint u = __float_as_uint(ev0); ue0 = (u >> 31) ? ~u : (u | 0x80000000u); }
    if (lane + 64 < m) { ev1 = bufv[r][lane + 64]; ec1 = bufc[r][lane + 64]; uint u = __float_as_uint(ev1); ue1 = (u >> 31) ? ~u : (u | 0x80000000u); }

    uint piv = 0u;
    int  cnt = m;
    for (int bit = 31; bit >= 0; --bit) {
        uint c = piv | (1u << bit);
        int k = __popcll(__ballot(ue0 >= c)) + __popcll(__ballot(ue1 >= c));
        if (k >= NK) {
            piv = c; cnt = k;
            if (!exact && cnt <= 48) break;
        }
    }
    if (lane == 0) cpos[r] = 0;
    // same-wave LDS program order: atomics below see the reset
    if (!exact && cnt <= 48) {
        if (lane < m      && ue0 >= piv) { int p = atomicAdd(&cpos[r], 1); bufv[r][p] = ev0; bufc[r][p] = ec0; }
        if (lane + 64 < m && ue1 >= piv) { int p = atomicAdd(&cpos[r], 1); bufv[r][p] = ev1; bufc[r][p] = ec1; }
        if (lane == 0) {
            bcnt[r] = cnt;
            thr[r] = (piv & 0x80000000u) ? __uint_as_float(piv ^ 0x80000000u)
                                         : __uint_as_float(~piv);
        }
    } else {
        if (ue0 > piv) { int p = atomicAdd(&cpos[r], 1); bufv[r][p] = ev0; bufc[r][p] = ec0; }
        if (ue1 > piv) { int p = atomicAdd(&cpos[r], 1); bufv[r][p] = ev1; bufc[r][p] = ec1; }
        if (ue0 == piv) { int p = atomicAdd(&cpos[r], 1); if (p < NK) { bufv[r][p] = ev0; bufc[r][p] = ec0; } }
        if (ue1 == piv) { int p = atomicAdd(&cpos[r], 1); if (p < NK) { bufv[r][p] = ev1; bufc[r][p] = ec1; } }
        if (lane == 0) {
            bcnt[r] = NK;
            thr[r] = (piv & 0x80000000u) ? __uint_as_float(piv ^ 0x80000000u)
                                         : __uint_as_float(~piv);
        }
    }
}

// ---------------------------------------------------------------------------
// Fused sim-GEMM (single-term bf16 MFMA) + filtered top-31 collection.
// 16 rows/block (A = 32 VGPRs), __launch_bounds__(256,6): 6 blocks/CU,
// occupancy ~70% (R19/R20-measured best). Selection: push + rare compaction.
// ---------------------------------------------------------------------------
__global__ __launch_bounds__(256, 6) void simtopk(
    const ushort* __restrict__ Xhi,
    float* __restrict__ ptv, int* __restrict__ ptc, int n)
{
    __shared__ float  bufv[16][CAPP];
    __shared__ ushort bufc[16][CAPP];
    __shared__ int   bcnt[16];
    __shared__ float thr[16];
    __shared__ int   cpos[16];

    const int slice = blockIdx.x & 7;
    const int i0 = (blockIdx.x >> 3) * 16;
    const int jspan = n / NSLICE;                 // 1250
    const int jbeg = slice * jspan, jend = jbeg + jspan;
    const int tid = threadIdx.x;
    const int w = tid >> 6, lane = tid & 63;
    const int l15 = lane & 15, l4 = lane >> 4;

    // A: 16 rows x K=256 -> 32 VGPRs
    bf16x8 Ahi[8];
    {
        int ir = min(i0 + l15, n - 1);
        const ushort* ph = Xhi + (size_t)ir * D_H2 + l4 * 8;
        #pragma unroll
        for (int ks = 0; ks < 8; ++ks)
            Ahi[ks] = *(const bf16x8*)(ph + ks * 32);
    }

    if (tid < 16) { thr[tid] = -1e30f; bcnt[tid] = 0; }
    __syncthreads();

    float tregs[4];
    #pragma unroll
    for (int q = 0; q < 4; ++q) tregs[q] = thr[l4 * 4 + q];

    for (int j0 = jbeg; j0 < jend; j0 += 64) {
        f32x4 acc = {0.f, 0.f, 0.f, 0.f};

        const int jc = j0 + w * 16 + l15;
        const size_t b0 = (size_t)min(jc, n - 1) * D_H2 + l4 * 8;

        bf16x8 bh[8];
        #pragma unroll
        for (int ks = 0; ks < 8; ++ks)
            bh[ks] = *(const bf16x8*)(Xhi + b0 + ks * 32);

        #pragma unroll
        for (int ks = 0; ks < 8; ++ks)
            acc = __builtin_amdgcn_mfma_f32_16x16x32_bf16(Ahi[ks], bh[ks], acc, 0, 0, 0);

        // fused filter: row = l4*4+q, col = jc
        #pragma unroll
        for (int q = 0; q < 4; ++q) {
            int r = l4 * 4 + q;
            float tq = tregs[q];
            float v0 = acc[q];
            if (v0 > tq && jc < jend) {
                int p = atomicAdd(&bcnt[r], 1);
                if (p < CAP) { bufv[r][p] = v0; bufc[r][p] = (ushort)jc; }
            }
        }
        __syncthreads();

        // compaction: wave w owns rows w*4..w*4+3
        #pragma unroll
        for (int rr = 0; rr < 4; ++rr) {
            int r = w * 4 + rr;
            if (bcnt[r] > TRIG) compact_row(bufv, bufc, bcnt, thr, cpos, r, lane, false);
        }
        __syncthreads();

        #pragma unroll
        for (int q = 0; q < 4; ++q) tregs[q] = thr[l4 * 4 + q];
    }

    // final exact compaction
    #pragma unroll
    for (int rr = 0; rr < 4; ++rr) {
        int r = w * 4 + rr;
        if (bcnt[r] > NK) compact_row(bufv, bufc, bcnt, thr, cpos, r, lane, true);
    }
    __syncthreads();

    for (int e = tid; e < 16 * NK; e += 256) {
        int r = e / NK, q = e - r * NK;
        if (i0 + r < n) {
            size_t o = ((size_t)slice * n + i0 + r) * NK + q;
            ptv[o] = bufv[r][q];
            ptc[o] = (int)bufc[r][q];
        }
    }
}

// ---------------------------------------------------------------------------
// Merge 8 partial top-31 lists -> final top-31 (one wave per row, 248 cands)
// ---------------------------------------------------------------------------
__global__ __launch_bounds__(256) void mergetop(
    const float* __restrict__ pv, const int* __restrict__ pc,
    float* __restrict__ tv, int* __restrict__ tc, int n)
{
    int row = blockIdx.x * 4 + (threadIdx.x >> 6);
    if (row >= n) return;
    int lane = threadIdx.x & 63;
    const int TOT = NSLICE * NK;  // 248
    float v0 = -1e30f, v1 = -1e30f, v2 = -1e30f, v3 = -1e30f;
    int c0 = 0, c1 = 0, c2 = 0, c3 = 0;
    #pragma unroll
    for (int qq = 0; qq < 4; ++qq) {
        int e = lane + qq * 64;
        if (e < TOT) {
            int s = e / NK, q = e - s * NK;
            size_t o = ((size_t)s * n + row) * NK + q;
            float vv = pv[o]; int cc = pc[o];
            if (qq == 0) { v0 = vv; c0 = cc; }
            else if (qq == 1) { v1 = vv; c1 = cc; }
            else if (qq == 2) { v2 = vv; c2 = cc; }
            else { v3 = vv; c3 = cc; }
        }
    }
    for (int t = 0; t < NK; ++t) {
        float m = v0; int sel = 0;
        if (v1 > m) { m = v1; sel = 1; }
        if (v2 > m) { m = v2; sel = 2; }
        if (v3 > m) { m = v3; sel = 3; }
        float bm = m;
        int bid = (lane << 2) | sel;
        #pragma unroll
        for (int off = 1; off < 64; off <<= 1) {
            float om = __shfl_xor(bm, off);
            int oid = __shfl_xor(bid, off);
            if (om > bm || (om == bm && oid < bid)) { bm = om; bid = oid; }
        }
        int wl = bid >> 2, slot = bid & 3;
        int wcol = (slot == 0) ? c0 : (slot == 1) ? c1 : (slot == 2) ? c2 : c3;
        int wc = __shfl(wcol, wl);
        if (lane == 0) { tv[(size_t)row * NK + t] = bm; tc[(size_t)row * NK + t] = wc; }
        if (lane == wl) {
            if (slot == 0) v0 = -1e30f;
            else if (slot == 1) v1 = -1e30f;
            else if (slot == 2) v2 = -1e30f;
            else v3 = -1e30f;
        }
    }
}

// ---------------------------------------------------------------------------
// Edge-parallel norm accumulation (hub-skew safe)
// ---------------------------------------------------------------------------
__global__ void knorm_edges(const float* __restrict__ tv, const int* __restrict__ tc,
                            float* __restrict__ nrm, int nedge)
{
    int e = blockIdx.x * 256 + threadIdx.x;
    if (e >= nedge) return;
    float v = tv[e];
    atomicAdd(&nrm[e / NK], v);
    atomicAdd(&nrm[tc[e]], v);
}

__global__ void knorm_fin(const float* __restrict__ nrm, float* __restrict__ rn, int n)
{
    int i = blockIdx.x * 256 + threadIdx.x;
    if (i < n) rn[i] = rsqrtf(nrm[i]);
}

// ---------------------------------------------------------------------------
// wk[e] = max(tv[e]*rn[row]*rn[col], 0) * (1-t)
// ---------------------------------------------------------------------------
__global__ void knn_weights(const float* __restrict__ tv, const int* __restrict__ tc,
                            const float* __restrict__ rn, const float* __restrict__ tptr,
                            float* __restrict__ wk, int nedge)
{
    int e = blockIdx.x * 256 + threadIdx.x;
    if (e >= nedge) return;
    int row = e / NK;
    int col = tc[e];
    wk[e] = fmaxf(tv[e] * rn[row] * rn[col], 0.f) * (1.f - *tptr);
}

// ---------------------------------------------------------------------------
// rev_prep: flatten rev-CSR indirection for hp phase B
// ---------------------------------------------------------------------------
__global__ void rev_prep(const int* __restrict__ eid2, const float* __restrict__ wk,
                         int* __restrict__ srcrev, float* __restrict__ wkrev, int n)
{
    int p = blockIdx.x * 256 + threadIdx.x;
    if (p >= n) return;
    int e = eid2[p];
    srcrev[p] = e / NK;
    wkrev[p] = wk[e];
}

// ---------------------------------------------------------------------------
// h_p[row] = [fwd knn + rev knn] + t*[adj], batched gathers (16 deep)
// ---------------------------------------------------------------------------
__global__ __launch_bounds__(256) void hp_kernel(
    const int* __restrict__ tc, const float* __restrict__ wk,
    const int* __restrict__ offs2, const int* __restrict__ cnt2,
    const int* __restrict__ srcrev, const float* __restrict__ wkrev,
    const ushort* __restrict__ hab,
    const int* __restrict__ aoffs, const int* __restrict__ acnt,
    const int* __restrict__ acol, const float* __restrict__ aval,
    const float* __restrict__ tptr, float* __restrict__ hp, int n)
{
    int row = blockIdx.x * 4 + (threadIdx.x >> 6);
    if (row >= n) return;
    int lane = threadIdx.x & 63;
    float t = *tptr;
    float a0 = 0.f, a1 = 0.f, a2 = 0.f, a3 = 0.f;

    // Phase A: fwd knn edges
    {
        const int base = row * NK;
        for (int j0 = 0; j0 < NK; j0 += 16) {
            int c[16]; float w[16];
            #pragma unroll
            for (int jj = 0; jj < 16; ++jj) {
                int j = j0 + jj;
                bool ok = j < NK;
                c[jj] = ok ? tc[base + j] : 0;
                w[jj] = ok ? wk[base + j] : 0.f;
            }
            ushort4 hv[16];
            #pragma unroll
            for (int jj = 0; jj < 16; ++jj)
                hv[jj] = *(const ushort4*)(hab + (size_t)c[jj] * D_H2 + (lane << 2));
            #pragma unroll
            for (int jj = 0; jj < 16; ++jj) {
                a0 = fmaf(w[jj], bf2f(hv[jj].x), a0);
                a1 = fmaf(w[jj], bf2f(hv[jj].y), a1);
                a2 = fmaf(w[jj], bf2f(hv[jj].z), a2);
                a3 = fmaf(w[jj], bf2f(hv[jj].w), a3);
            }
        }
    }
    // Phase B: rev knn edges (affine srcrev/wkrev)
    {
        int st = offs2[row], m = cnt2[row];
        for (int p0 = 0; p0 < m; p0 += 16) {
            int c[16]; float w[16];
            #pragma unroll
            for (int jj = 0; jj < 16; ++jj) {
                int p = p0 + jj;
                bool ok = p < m;
                c[jj] = ok ? srcrev[st + p] : 0;
                w[jj] = ok ? wkrev[st + p] : 0.f;
            }
            ushort4 hv[16];
            #pragma unroll
            for (int jj = 0; jj < 16; ++jj)
                hv[jj] = *(const ushort4*)(hab + (size_t)c[jj] * D_H2 + (lane << 2));
            #pragma unroll
            for (int jj = 0; jj < 16; ++jj) {
                a0 = fmaf(w[jj], bf2f(hv[jj].x), a0);
                a1 = fmaf(w[jj], bf2f(hv[jj].y), a1);
                a2 = fmaf(w[jj], bf2f(hv[jj].z), a2);
                a3 = fmaf(w[jj], bf2f(hv[jj].w), a3);
            }
        }
    }
    // Phase C: original adj edges, scaled by t
    {
        int st = aoffs[row], m = acnt[row];
        for (int p0 = 0; p0 < m; p0 += 16) {
            int c[16]; float w[16];
            #pragma unroll
            for (int jj = 0; jj < 16; ++jj) {
                int p = p0 + jj;
                bool ok = p < m;
                c[jj] = ok ? acol[st + p] : 0;
                w[jj] = ok ? aval[st + p] * t : 0.f;
            }
            ushort4 hv[16];
            #pragma unroll
            for (int jj = 0; jj < 16; ++jj)
                hv[jj] = *(const ushort4*)(hab + (size_t)c[jj] * D_H2 + (lane << 2));
            #pragma unroll
            for (int jj = 0; jj < 16; ++jj) {
                a0 = fmaf(w[jj], bf2f(hv[jj].x), a0);
                a1 = fmaf(w[jj], bf2f(hv[jj].y), a1);
                a2 = fmaf(w[jj], bf2f(hv[jj].z), a2);
                a3 = fmaf(w[jj], bf2f(hv[jj].w), a3);
            }
        }
    }
    *(float4*)(hp + (size_t)row * D_H2 + (lane << 2)) = make_float4(a0, a1, a2, a3);
}

// ---------------------------------------------------------------------------
extern "C" void kernel_launch(void* const* d_in, const int* in_sizes, int n_in,
                              void* d_out, int out_size, void* d_ws, size_t ws_size,
                              hipStream_t stream)
{
    const float* feature = (const float*)d_in[0];
    const int*   arows   = (const int*)d_in[1];
    const int*   acols   = (const int*)d_in[2];
    const float* avals   = (const float*)d_in[3];
    const float* W1      = (const float*)d_in[4];
    const float* b1      = (const float*)d_in[5];
    const float* W2      = (const float*)d_in[6];
    const float* b2      = (const float*)d_in[7];
    const float* tptr    = (const float*)d_in[8];

    float* hs = (float*)d_out;                            // [N, 256]
    float* hp = (float*)d_out + (size_t)N_NODES * D_H2;   // [N, 256]

    char* ws = (char*)d_ws;
    // R0 [0..10.24 MB): fb16 -> later xhi (dead after simtopk) -> wk
    ushort* fb16 = (ushort*)(ws + 0);            // [cast..gemm1]
    ushort* xhi  = (ushort*)(ws + 0);            // [spmm_norm..simtopk]
    float*  wk   = (float*) (ws + 0);            // [knn_weights..hp]
    ushort* hsb  = (ushort*)(ws + 10240000);     // 5.12 MB [gemm2..spmm_norm]
    float*  ptv  = (float*) (ws + 10240000);     // 9.92 MB [simtopk..mergetop]
    int*    srcrev = (int*) (ws + 10240000);     // [rev_prep..hp] (ptv dead)
    float*  wkrev  = (float*)(ws + 11480000);    // [rev_prep..hp]
    // R1 [20.48..40.96 MB): h1b16 -> later ptc / hab
    ushort* h1b16 = (ushort*)(ws + 20480000);    // 10.24 MB [gemm1..gemm2]
    int*    ptc   = (int*)   (ws + 20480000);    // 9.92 MB [simtopk..mergetop]
    ushort* hab   = (ushort*)(ws + 30720000);    // 5.12 MB [spmm_norm..hp]
    // R2 small persistent
    float*  tv    = (float*)(ws + 40960000);     // 1,240,000 B
    int*    tc    = (int*)  (ws + 42200000);     // 1,240,000 B
    float*  rn    = (float*)(ws + 43440000);     // 40,000 B
    int*    cnt1  = (int*)  (ws + 43480000);
    int*    offs1 = (int*)  (ws + 43520000);
    int*    next1 = (int*)  (ws + 43560000);
    int*    ccol1 = (int*)  (ws + 43600000);     // 1,280,000 B
    float*  cval1 = (float*)(ws + 44880000);     // 1,280,000 B
    int*    cnt2  = (int*)  (ws + 46160000);
    int*    offs2 = (int*)  (ws + 46200000);
    int*    next2 = (int*)  (ws + 46240000);
    int*    eid2  = (int*)  (ws + 46280000);     // 1,240,000 B
    ushort* w1t   = (ushort*)(ws + 47520000);    // 524,288 B
    ushort* w2t   = (ushort*)(ws + 48044288);    // 262,144 B
    float*  nrm   = (float*)(ws + 48306432);     // 40,000 B -> 48,346,432 total

    hipMemsetAsync(cnt1, 0, N_NODES * sizeof(int), stream);
    hipMemsetAsync(cnt2, 0, N_NODES * sizeof(int), stream);
    hipMemsetAsync(nrm,  0, N_NODES * sizeof(float), stream);

    // bf16 casts
    tobf16_plain<<<(N_NODES * D_IN / 4 + 255) / 256, 256, 0, stream>>>(
        feature, fb16, N_NODES * D_IN / 4);
    tobf16_transpose<<<(D_H1 * D_IN / 4 + 255) / 256, 256, 0, stream>>>(
        W1, D_IN, D_H1, w1t);
    tobf16_transpose<<<(D_H2 * D_H1 / 4 + 255) / 256, 256, 0, stream>>>(
        W2, D_H1, D_H2, w2t);

    // MLP via single-term bf16 MFMA
    gemm_mfma<<<dim3((N_NODES + 31) / 32, D_H1 / 128), 256, 0, stream>>>(
        fb16, w1t, b1, N_NODES, D_H1, D_IN, 1, nullptr, nullptr, h1b16);
    gemm_mfma<<<dim3((N_NODES + 31) / 32, D_H2 / 128), 256, 0, stream>>>(
        h1b16, w2t, b2, N_NODES, D_H2, D_H1, 0, hs, hsb, nullptr);

    // adj CSR + fused spmm/rownorm -> xhi, hab
    hist_kernel<<<(N_EDGE + 255) / 256, 256, 0, stream>>>(arows, cnt1, N_EDGE);
    scan_kernel<<<1, 256, 0, stream>>>(cnt1, offs1, next1, N_NODES);
    scatter_adj<<<(N_EDGE + 255) / 256, 256, 0, stream>>>(
        arows, acols, avals, next1, ccol1, cval1, N_EDGE);
    spmm_norm<<<(N_NODES + 3) / 4, 256, 0, stream>>>(
        offs1, cnt1, ccol1, cval1, hsb, xhi, hab, N_NODES);

    // cosine sim + top-k (16-row blocks, XCD-pinned slices)
    simtopk<<<((N_NODES + 15) / 16) * NSLICE, 256, 0, stream>>>(
        xhi, ptv, ptc, N_NODES);
    mergetop<<<(N_NODES + 3) / 4, 256, 0, stream>>>(ptv, ptc, tv, tc, N_NODES);

    // reverse CSR over knn entries
    hist_kernel<<<(N_NODES * NK + 255) / 256, 256, 0, stream>>>(tc, cnt2, N_NODES * NK);
    scan_kernel<<<1, 256, 0, stream>>>(cnt2, offs2, next2, N_NODES);
    scatter_knn<<<(N_NODES * NK + 255) / 256, 256, 0, stream>>>(
        tc, next2, eid2, N_NODES * NK);

    // degree norm (edge-parallel, hub-safe), weights, rev flatten, propagation
    knorm_edges<<<(N_NODES * NK + 255) / 256, 256, 0, stream>>>(
        tv, tc, nrm, N_NODES * NK);
    knorm_fin<<<(N_NODES + 255) / 256, 256, 0, stream>>>(nrm, rn, N_NODES);
    knn_weights<<<(N_NODES * NK + 255) / 256, 256, 0, stream>>>(
        tv, tc, rn, tptr, wk, N_NODES * NK);
    rev_prep<<<(N_NODES * NK + 255) / 256, 256, 0, stream>>>(
        eid2, wk, srcrev, wkrev, N_NODES * NK);
    hp_kernel<<<(N_NODES + 3) / 4, 256, 0, stream>>>(
        tc, wk, offs2, cnt2, srcrev, wkrev, hab, offs1, cnt1, ccol1, cval1,
        tptr, hp, N_NODES);
}

// Round 23
// 1145.370 us; speedup vs baseline: 1.0979x; 1.0752x over previous
//
#include <hip/hip_runtime.h>
#include <math.h>

#define N_NODES 10000
#define D_IN    512
#define D_H1    512
#define D_H2    256
#define N_EDGE  320000
#define NK      31
#define NSLICE  8
#define CAP     128
#define CAPP    129
#define TRIG    64

typedef short bf16x8 __attribute__((ext_vector_type(8)));
typedef float f32x4  __attribute__((ext_vector_type(4)));

static __device__ __forceinline__ ushort f2bf(float x) {
    uint u = __float_as_uint(x);
    uint r = (u + 0x7fffu + ((u >> 16) & 1u)) >> 16;
    return (ushort)r;
}
static __device__ __forceinline__ float bf2f(ushort h) {
    return __uint_as_float(((uint)h) << 16);
}

// ---------------------------------------------------------------------------
// f32 -> bf16 elementwise (4 elems/thread)
// ---------------------------------------------------------------------------
__global__ __launch_bounds__(256) void tobf16_plain(
    const float* __restrict__ F, ushort* __restrict__ H, int nquads)
{
    int q = blockIdx.x * 256 + threadIdx.x;
    if (q >= nquads) return;
    float4 v = *(const float4*)(F + (size_t)q * 4);
    *(ushort4*)(H + (size_t)q * 4) =
        make_ushort4(f2bf(v.x), f2bf(v.y), f2bf(v.z), f2bf(v.w));
}

// ---------------------------------------------------------------------------
// W [K,N] f32 -> Bt [N,K] bf16 (transpose + cast)
// ---------------------------------------------------------------------------
__global__ __launch_bounds__(256) void tobf16_transpose(
    const float* __restrict__ W, int K, int N, ushort* __restrict__ Bh)
{
    int q = blockIdx.x * 256 + threadIdx.x;
    int kq4 = K >> 2;
    if (q >= N * kq4) return;
    int nrow = q / kq4, kq = q - nrow * kq4;
    ushort h[4];
    #pragma unroll
    for (int j = 0; j < 4; ++j)
        h[j] = f2bf(W[(size_t)(kq * 4 + j) * N + nrow]);
    *(ushort4*)(Bh + (size_t)nrow * K + kq * 4) = make_ushort4(h[0], h[1], h[2], h[3]);
}

// ---------------------------------------------------------------------------
// MFMA GEMM (single-term bf16): C[M,N] = act(A @ Bt^T + bias).
// mode 1: relu, write bf16. mode 0: write f32 C + bf16 Cbf.
// ---------------------------------------------------------------------------
__global__ __launch_bounds__(256) void gemm_mfma(
    const ushort* __restrict__ A, const ushort* __restrict__ Bt,
    const float* __restrict__ bias, int M, int N, int K, int mode,
    float* __restrict__ C, ushort* __restrict__ Cbf, ushort* __restrict__ Cb16)
{
    const int i0 = blockIdx.x * 32, jb = blockIdx.y * 128;
    const int tid = threadIdx.x, w = tid >> 6, lane = tid & 63;
    const int l15 = lane & 15, l4 = lane >> 4;
    const int ir0 = min(i0 + l15, M - 1), ir1 = min(i0 + 16 + l15, M - 1);
    const int jc = jb + w * 32 + l15;

    const ushort* a0 = A + (size_t)ir0 * K + l4 * 8;
    const ushort* a1 = A + (size_t)ir1 * K + l4 * 8;
    const ushort* b0 = Bt + (size_t)jc * K + l4 * 8;
    const ushort* b1 = Bt + (size_t)(jc + 16) * K + l4 * 8;

    f32x4 acc00 = {0.f, 0.f, 0.f, 0.f};
    f32x4 acc01 = acc00, acc10 = acc00, acc11 = acc00;

    for (int k0 = 0; k0 < K; k0 += 32) {
        bf16x8 A0 = *(const bf16x8*)(a0 + k0);
        bf16x8 A1 = *(const bf16x8*)(a1 + k0);
        bf16x8 B0 = *(const bf16x8*)(b0 + k0);
        bf16x8 B1 = *(const bf16x8*)(b1 + k0);
        acc00 = __builtin_amdgcn_mfma_f32_16x16x32_bf16(A0, B0, acc00, 0, 0, 0);
        acc10 = __builtin_amdgcn_mfma_f32_16x16x32_bf16(A1, B0, acc10, 0, 0, 0);
        acc01 = __builtin_amdgcn_mfma_f32_16x16x32_bf16(A0, B1, acc01, 0, 0, 0);
        acc11 = __builtin_amdgcn_mfma_f32_16x16x32_bf16(A1, B1, acc11, 0, 0, 0);
    }

    float bs0 = bias[jc], bs1 = bias[jc + 16];
    #pragma unroll
    for (int rt = 0; rt < 2; ++rt) {
        #pragma unroll
        for (int q = 0; q < 4; ++q) {
            int i = i0 + rt * 16 + l4 * 4 + q;
            if (i >= M) continue;
            float v0 = (rt ? acc10[q] : acc00[q]) + bs0;
            float v1 = (rt ? acc11[q] : acc01[q]) + bs1;
            if (mode == 1) {
                v0 = fmaxf(v0, 0.f); v1 = fmaxf(v1, 0.f);
                Cb16[(size_t)i * N + jc]      = f2bf(v0);
                Cb16[(size_t)i * N + jc + 16] = f2bf(v1);
            } else {
                C[(size_t)i * N + jc]        = v0;
                C[(size_t)i * N + jc + 16]   = v1;
                Cbf[(size_t)i * N + jc]      = f2bf(v0);
                Cbf[(size_t)i * N + jc + 16] = f2bf(v1);
            }
        }
    }
}

// ---------------------------------------------------------------------------
// CSR build helpers
// ---------------------------------------------------------------------------
__global__ void hist_kernel(const int* __restrict__ idx, int* __restrict__ cnt, int n)
{
    int i = blockIdx.x * 256 + threadIdx.x;
    if (i < n) atomicAdd(&cnt[idx[i]], 1);
}

__global__ __launch_bounds__(256) void scan_kernel(
    const int* __restrict__ cnt, int* __restrict__ offs, int* __restrict__ nxt, int n)
{
    __shared__ int ssum[256];
    int t = threadIdx.x;
    int per = (n + 255) >> 8;
    int lo = t * per, hi = min(lo + per, n);
    int s = 0;
    for (int i = lo; i < hi; ++i) s += cnt[i];
    ssum[t] = s;
    __syncthreads();
    if (t == 0) {
        int run = 0;
        for (int i = 0; i < 256; ++i) { int x = ssum[i]; ssum[i] = run; run += x; }
    }
    __syncthreads();
    int run = ssum[t];
    for (int i = lo; i < hi; ++i) { offs[i] = run; nxt[i] = run; run += cnt[i]; }
}

__global__ void scatter_adj(const int* __restrict__ rows, const int* __restrict__ cols,
                            const float* __restrict__ vals, int* __restrict__ nxt,
                            int* __restrict__ ccol, float* __restrict__ cval, int n)
{
    int e = blockIdx.x * 256 + threadIdx.x;
    if (e >= n) return;
    int p = atomicAdd(&nxt[rows[e]], 1);
    ccol[p] = cols[e];
    cval[p] = vals[e];
}

__global__ void scatter_knn(const int* __restrict__ tc, int* __restrict__ nxt,
                            int* __restrict__ eid, int n)
{
    int e = blockIdx.x * 256 + threadIdx.x;
    if (e >= n) return;
    int p = atomicAdd(&nxt[tc[e]], 1);
    eid[p] = e;
}

// ---------------------------------------------------------------------------
// CSR spmm over bf16 H + FUSED row L2-normalize: writes xhi (normalized bf16)
// and hab (raw bf16) directly.
// ---------------------------------------------------------------------------
__global__ __launch_bounds__(256) void spmm_norm(
    const int* __restrict__ offs, const int* __restrict__ cnt,
    const int* __restrict__ cols, const float* __restrict__ vals,
    const ushort* __restrict__ Hb, ushort* __restrict__ xhi,
    ushort* __restrict__ hab, int n)
{
    int row = blockIdx.x * 4 + (threadIdx.x >> 6);
    if (row >= n) return;
    int lane = threadIdx.x & 63;
    int st = offs[row], m = cnt[row];
    float a0 = 0.f, a1 = 0.f, a2 = 0.f, a3 = 0.f;
    for (int p0 = 0; p0 < m; p0 += 16) {
        int c[16]; float v[16];
        #pragma unroll
        for (int jj = 0; jj < 16; ++jj) {
            int p = p0 + jj;
            bool ok = p < m;
            c[jj] = ok ? cols[st + p] : 0;
            v[jj] = ok ? vals[st + p] : 0.f;
        }
        ushort4 hv[16];
        #pragma unroll
        for (int jj = 0; jj < 16; ++jj)
            hv[jj] = *(const ushort4*)(Hb + (size_t)c[jj] * D_H2 + (lane << 2));
        #pragma unroll
        for (int jj = 0; jj < 16; ++jj) {
            a0 = fmaf(v[jj], bf2f(hv[jj].x), a0);
            a1 = fmaf(v[jj], bf2f(hv[jj].y), a1);
            a2 = fmaf(v[jj], bf2f(hv[jj].z), a2);
            a3 = fmaf(v[jj], bf2f(hv[jj].w), a3);
        }
    }
    *(ushort4*)(hab + (size_t)row * D_H2 + (lane << 2)) =
        make_ushort4(f2bf(a0), f2bf(a1), f2bf(a2), f2bf(a3));
    float s = a0 * a0 + a1 * a1 + a2 * a2 + a3 * a3;
    #pragma unroll
    for (int mm = 1; mm < 64; mm <<= 1) s += __shfl_xor(s, mm);
    float inv = 1.f / fmaxf(sqrtf(s), 1e-12f);
    *(ushort4*)(xhi + (size_t)row * D_H2 + (lane << 2)) =
        make_ushort4(f2bf(a0 * inv), f2bf(a1 * inv),
                     f2bf(a2 * inv), f2bf(a3 * inv));
}

// ---------------------------------------------------------------------------
// Wave-parallel top-31 compaction (bisection over monotone uint codes).
// cols stored as ushort (N < 65536). CAP = 128 = 2 x 64 lanes.
// ---------------------------------------------------------------------------
__device__ __forceinline__ void compact_row(
    float (*bufv)[CAPP], ushort (*bufc)[CAPP], int* bcnt, float* thr, int* cpos,
    int r, int lane, bool exact)
{
    int m = min(bcnt[r], CAP);
    float ev0 = 0.f, ev1 = 0.f;
    ushort ec0 = 0, ec1 = 0;
    uint  ue0 = 0u, ue1 = 0u;
    if (lane < m)      { ev0 = bufv[r][lane];      ec0 = bufc[r][lane];      uint u = __float_as_uint(ev0); ue0 = (u >> 31) ? ~u : (u | 0x80000000u); }
    if (lane + 64 < m) { ev1 = bufv[r][lane + 64]; ec1 = bufc[r][lane + 64]; uint u = __float_as_uint(ev1); ue1 = (u >> 31) ? ~u : (u | 0x80000000u); }

    uint piv = 0u;
    int  cnt = m;
    for (int bit = 31; bit >= 0; --bit) {
        uint c = piv | (1u << bit);
        int k = __popcll(__ballot(ue0 >= c)) + __popcll(__ballot(ue1 >= c));
        if (k >= NK) {
            piv = c; cnt = k;
            if (!exact && cnt <= 48) break;
        }
    }
    if (lane == 0) cpos[r] = 0;
    // same-wave LDS program order: atomics below see the reset
    if (!exact && cnt <= 48) {
        if (lane < m      && ue0 >= piv) { int p = atomicAdd(&cpos[r], 1); bufv[r][p] = ev0; bufc[r][p] = ec0; }
        if (lane + 64 < m && ue1 >= piv) { int p = atomicAdd(&cpos[r], 1); bufv[r][p] = ev1; bufc[r][p] = ec1; }
        if (lane == 0) {
            bcnt[r] = cnt;
            thr[r] = (piv & 0x80000000u) ? __uint_as_float(piv ^ 0x80000000u)
                                         : __uint_as_float(~piv);
        }
    } else {
        if (ue0 > piv) { int p = atomicAdd(&cpos[r], 1); bufv[r][p] = ev0; bufc[r][p] = ec0; }
        if (ue1 > piv) { int p = atomicAdd(&cpos[r], 1); bufv[r][p] = ev1; bufc[r][p] = ec1; }
        if (ue0 == piv) { int p = atomicAdd(&cpos[r], 1); if (p < NK) { bufv[r][p] = ev0; bufc[r][p] = ec0; } }
        if (ue1 == piv) { int p = atomicAdd(&cpos[r], 1); if (p < NK) { bufv[r][p] = ev1; bufc[r][p] = ec1; } }
        if (lane == 0) {
            bcnt[r] = NK;
            thr[r] = (piv & 0x80000000u) ? __uint_as_float(piv ^ 0x80000000u)
                                         : __uint_as_float(~piv);
        }
    }
}

// ---------------------------------------------------------------------------
// Fused sim-GEMM (single-term bf16 MFMA) + filtered top-31 collection.
// 16 rows/block (A = 32 VGPRs), __launch_bounds__(256,6): 6 blocks/CU,
// occupancy ~70% (R19/R20-measured best). Selection: push + rare compaction.
// ---------------------------------------------------------------------------
__global__ __launch_bounds__(256, 6) void simtopk(
    const ushort* __restrict__ Xhi,
    float* __restrict__ ptv, int* __restrict__ ptc, int n)
{
    __shared__ float  bufv[16][CAPP];
    __shared__ ushort bufc[16][CAPP];
    __shared__ int   bcnt[16];
    __shared__ float thr[16];
    __shared__ int   cpos[16];

    const int slice = blockIdx.x & 7;
    const int i0 = (blockIdx.x >> 3) * 16;
    const int jspan = n / NSLICE;                 // 1250
    const int jbeg = slice * jspan, jend = jbeg + jspan;
    const int tid = threadIdx.x;
    const int w = tid >> 6, lane = tid & 63;
    const int l15 = lane & 15, l4 = lane >> 4;

    // A: 16 rows x K=256 -> 32 VGPRs
    bf16x8 Ahi[8];
    {
        int ir = min(i0 + l15, n - 1);
        const ushort* ph = Xhi + (size_t)ir * D_H2 + l4 * 8;
        #pragma unroll
        for (int ks = 0; ks < 8; ++ks)
            Ahi[ks] = *(const bf16x8*)(ph + ks * 32);
    }

    if (tid < 16) { thr[tid] = -1e30f; bcnt[tid] = 0; }
    __syncthreads();

    float tregs[4];
    #pragma unroll
    for (int q = 0; q < 4; ++q) tregs[q] = thr[l4 * 4 + q];

    for (int j0 = jbeg; j0 < jend; j0 += 64) {
        f32x4 acc = {0.f, 0.f, 0.f, 0.f};

        const int jc = j0 + w * 16 + l15;
        const size_t b0 = (size_t)min(jc, n - 1) * D_H2 + l4 * 8;

        bf16x8 bh[8];
        #pragma unroll
        for (int ks = 0; ks < 8; ++ks)
            bh[ks] = *(const bf16x8*)(Xhi + b0 + ks * 32);

        #pragma unroll
        for (int ks = 0; ks < 8; ++ks)
            acc = __builtin_amdgcn_mfma_f32_16x16x32_bf16(Ahi[ks], bh[ks], acc, 0, 0, 0);

        // fused filter: row = l4*4+q, col = jc
        #pragma unroll
        for (int q = 0; q < 4; ++q) {
            int r = l4 * 4 + q;
            float tq = tregs[q];
            float v0 = acc[q];
            if (v0 > tq && jc < jend) {
                int p = atomicAdd(&bcnt[r], 1);
                if (p < CAP) { bufv[r][p] = v0; bufc[r][p] = (ushort)jc; }
            }
        }
        __syncthreads();

        // compaction: wave w owns rows w*4..w*4+3
        #pragma unroll
        for (int rr = 0; rr < 4; ++rr) {
            int r = w * 4 + rr;
            if (bcnt[r] > TRIG) compact_row(bufv, bufc, bcnt, thr, cpos, r, lane, false);
        }
        __syncthreads();

        #pragma unroll
        for (int q = 0; q < 4; ++q) tregs[q] = thr[l4 * 4 + q];
    }

    // final exact compaction
    #pragma unroll
    for (int rr = 0; rr < 4; ++rr) {
        int r = w * 4 + rr;
        if (bcnt[r] > NK) compact_row(bufv, bufc, bcnt, thr, cpos, r, lane, true);
    }
    __syncthreads();

    for (int e = tid; e < 16 * NK; e += 256) {
        int r = e / NK, q = e - r * NK;
        if (i0 + r < n) {
            size_t o = ((size_t)slice * n + i0 + r) * NK + q;
            ptv[o] = bufv[r][q];
            ptc[o] = (int)bufc[r][q];
        }
    }
}

// ---------------------------------------------------------------------------
// Merge 8 partial top-31 lists -> final top-31 (one wave per row, 248 cands)
// FUSED: per selected edge, also accumulate degree-norm (nrm) and the
// reverse-CSR histogram (cnt2) -- removes two 310k-edge passes/launches.
// ---------------------------------------------------------------------------
__global__ __launch_bounds__(256) void mergetop(
    const float* __restrict__ pv, const int* __restrict__ pc,
    float* __restrict__ tv, int* __restrict__ tc,
    float* __restrict__ nrm, int* __restrict__ cnt2, int n)
{
    int row = blockIdx.x * 4 + (threadIdx.x >> 6);
    if (row >= n) return;
    int lane = threadIdx.x & 63;
    const int TOT = NSLICE * NK;  // 248
    float v0 = -1e30f, v1 = -1e30f, v2 = -1e30f, v3 = -1e30f;
    int c0 = 0, c1 = 0, c2 = 0, c3 = 0;
    #pragma unroll
    for (int qq = 0; qq < 4; ++qq) {
        int e = lane + qq * 64;
        if (e < TOT) {
            int s = e / NK, q = e - s * NK;
            size_t o = ((size_t)s * n + row) * NK + q;
            float vv = pv[o]; int cc = pc[o];
            if (qq == 0) { v0 = vv; c0 = cc; }
            else if (qq == 1) { v1 = vv; c1 = cc; }
            else if (qq == 2) { v2 = vv; c2 = cc; }
            else { v3 = vv; c3 = cc; }
        }
    }
    float rowsum = 0.f;
    for (int t = 0; t < NK; ++t) {
        float m = v0; int sel = 0;
        if (v1 > m) { m = v1; sel = 1; }
        if (v2 > m) { m = v2; sel = 2; }
        if (v3 > m) { m = v3; sel = 3; }
        float bm = m;
        int bid = (lane << 2) | sel;
        #pragma unroll
        for (int off = 1; off < 64; off <<= 1) {
            float om = __shfl_xor(bm, off);
            int oid = __shfl_xor(bid, off);
            if (om > bm || (om == bm && oid < bid)) { bm = om; bid = oid; }
        }
        int wl = bid >> 2, slot = bid & 3;
        int wcol = (slot == 0) ? c0 : (slot == 1) ? c1 : (slot == 2) ? c2 : c3;
        int wc = __shfl(wcol, wl);
        if (lane == 0) {
            tv[(size_t)row * NK + t] = bm;
            tc[(size_t)row * NK + t] = wc;
            rowsum += bm;
            atomicAdd(&nrm[wc], bm);     // col-side degree norm
            atomicAdd(&cnt2[wc], 1);     // reverse-CSR histogram
        }
        if (lane == wl) {
            if (slot == 0) v0 = -1e30f;
            else if (slot == 1) v1 = -1e30f;
            else if (slot == 2) v2 = -1e30f;
            else v3 = -1e30f;
        }
    }
    if (lane == 0) atomicAdd(&nrm[row], rowsum);  // row-side degree norm
}

__global__ void knorm_fin(const float* __restrict__ nrm, float* __restrict__ rn, int n)
{
    int i = blockIdx.x * 256 + threadIdx.x;
    if (i < n) rn[i] = rsqrtf(nrm[i]);
}

// ---------------------------------------------------------------------------
// wk[e] = max(tv[e]*rn[row]*rn[col], 0) * (1-t)
// ---------------------------------------------------------------------------
__global__ void knn_weights(const float* __restrict__ tv, const int* __restrict__ tc,
                            const float* __restrict__ rn, const float* __restrict__ tptr,
                            float* __restrict__ wk, int nedge)
{
    int e = blockIdx.x * 256 + threadIdx.x;
    if (e >= nedge) return;
    int row = e / NK;
    int col = tc[e];
    wk[e] = fmaxf(tv[e] * rn[row] * rn[col], 0.f) * (1.f - *tptr);
}

// ---------------------------------------------------------------------------
// rev_prep: flatten rev-CSR indirection for hp phase B
// ---------------------------------------------------------------------------
__global__ void rev_prep(const int* __restrict__ eid2, const float* __restrict__ wk,
                         int* __restrict__ srcrev, float* __restrict__ wkrev, int n)
{
    int p = blockIdx.x * 256 + threadIdx.x;
    if (p >= n) return;
    int e = eid2[p];
    srcrev[p] = e / NK;
    wkrev[p] = wk[e];
}

// ---------------------------------------------------------------------------
// h_p[row] = [fwd knn + rev knn] + t*[adj], batched gathers (16 deep)
// ---------------------------------------------------------------------------
__global__ __launch_bounds__(256) void hp_kernel(
    const int* __restrict__ tc, const float* __restrict__ wk,
    const int* __restrict__ offs2, const int* __restrict__ cnt2,
    const int* __restrict__ srcrev, const float* __restrict__ wkrev,
    const ushort* __restrict__ hab,
    const int* __restrict__ aoffs, const int* __restrict__ acnt,
    const int* __restrict__ acol, const float* __restrict__ aval,
    const float* __restrict__ tptr, float* __restrict__ hp, int n)
{
    int row = blockIdx.x * 4 + (threadIdx.x >> 6);
    if (row >= n) return;
    int lane = threadIdx.x & 63;
    float t = *tptr;
    float a0 = 0.f, a1 = 0.f, a2 = 0.f, a3 = 0.f;

    // Phase A: fwd knn edges
    {
        const int base = row * NK;
        for (int j0 = 0; j0 < NK; j0 += 16) {
            int c[16]; float w[16];
            #pragma unroll
            for (int jj = 0; jj < 16; ++jj) {
                int j = j0 + jj;
                bool ok = j < NK;
                c[jj] = ok ? tc[base + j] : 0;
                w[jj] = ok ? wk[base + j] : 0.f;
            }
            ushort4 hv[16];
            #pragma unroll
            for (int jj = 0; jj < 16; ++jj)
                hv[jj] = *(const ushort4*)(hab + (size_t)c[jj] * D_H2 + (lane << 2));
            #pragma unroll
            for (int jj = 0; jj < 16; ++jj) {
                a0 = fmaf(w[jj], bf2f(hv[jj].x), a0);
                a1 = fmaf(w[jj], bf2f(hv[jj].y), a1);
                a2 = fmaf(w[jj], bf2f(hv[jj].z), a2);
                a3 = fmaf(w[jj], bf2f(hv[jj].w), a3);
            }
        }
    }
    // Phase B: rev knn edges (affine srcrev/wkrev)
    {
        int st = offs2[row], m = cnt2[row];
        for (int p0 = 0; p0 < m; p0 += 16) {
            int c[16]; float w[16];
            #pragma unroll
            for (int jj = 0; jj < 16; ++jj) {
                int p = p0 + jj;
                bool ok = p < m;
                c[jj] = ok ? srcrev[st + p] : 0;
                w[jj] = ok ? wkrev[st + p] : 0.f;
            }
            ushort4 hv[16];
            #pragma unroll
            for (int jj = 0; jj < 16; ++jj)
                hv[jj] = *(const ushort4*)(hab + (size_t)c[jj] * D_H2 + (lane << 2));
            #pragma unroll
            for (int jj = 0; jj < 16; ++jj) {
                a0 = fmaf(w[jj], bf2f(hv[jj].x), a0);
                a1 = fmaf(w[jj], bf2f(hv[jj].y), a1);
                a2 = fmaf(w[jj], bf2f(hv[jj].z), a2);
                a3 = fmaf(w[jj], bf2f(hv[jj].w), a3);
            }
        }
    }
    // Phase C: original adj edges, scaled by t
    {
        int st = aoffs[row], m = acnt[row];
        for (int p0 = 0; p0 < m; p0 += 16) {
            int c[16]; float w[16];
            #pragma unroll
            for (int jj = 0; jj < 16; ++jj) {
                int p = p0 + jj;
                bool ok = p < m;
                c[jj] = ok ? acol[st + p] : 0;
                w[jj] = ok ? aval[st + p] * t : 0.f;
            }
            ushort4 hv[16];
            #pragma unroll
            for (int jj = 0; jj < 16; ++jj)
                hv[jj] = *(const ushort4*)(hab + (size_t)c[jj] * D_H2 + (lane << 2));
            #pragma unroll
            for (int jj = 0; jj < 16; ++jj) {
                a0 = fmaf(w[jj], bf2f(hv[jj].x), a0);
                a1 = fmaf(w[jj], bf2f(hv[jj].y), a1);
                a2 = fmaf(w[jj], bf2f(hv[jj].z), a2);
                a3 = fmaf(w[jj], bf2f(hv[jj].w), a3);
            }
        }
    }
    *(float4*)(hp + (size_t)row * D_H2 + (lane << 2)) = make_float4(a0, a1, a2, a3);
}

// ---------------------------------------------------------------------------
extern "C" void kernel_launch(void* const* d_in, const int* in_sizes, int n_in,
                              void* d_out, int out_size, void* d_ws, size_t ws_size,
                              hipStream_t stream)
{
    const float* feature = (const float*)d_in[0];
    const int*   arows   = (const int*)d_in[1];
    const int*   acols   = (const int*)d_in[2];
    const float* avals   = (const float*)d_in[3];
    const float* W1      = (const float*)d_in[4];
    const float* b1      = (const float*)d_in[5];
    const float* W2      = (const float*)d_in[6];
    const float* b2      = (const float*)d_in[7];
    const float* tptr    = (const float*)d_in[8];

    float* hs = (float*)d_out;                            // [N, 256]
    float* hp = (float*)d_out + (size_t)N_NODES * D_H2;   // [N, 256]

    char* ws = (char*)d_ws;
    // R0 [0..10.24 MB): fb16 -> later xhi (dead after simtopk) -> wk
    ushort* fb16 = (ushort*)(ws + 0);            // [cast..gemm1]
    ushort* xhi  = (ushort*)(ws + 0);            // [spmm_norm..simtopk]
    float*  wk   = (float*) (ws + 0);            // [knn_weights..hp]
    ushort* hsb  = (ushort*)(ws + 10240000);     // 5.12 MB [gemm2..spmm_norm]
    float*  ptv  = (float*) (ws + 10240000);     // 9.92 MB [simtopk..mergetop]
    int*    srcrev = (int*) (ws + 10240000);     // [rev_prep..hp] (ptv dead)
    float*  wkrev  = (float*)(ws + 11480000);    // [rev_prep..hp]
    // R1 [20.48..40.96 MB): h1b16 -> later ptc / hab
    ushort* h1b16 = (ushort*)(ws + 20480000);    // 10.24 MB [gemm1..gemm2]
    int*    ptc   = (int*)   (ws + 20480000);    // 9.92 MB [simtopk..mergetop]
    ushort* hab   = (ushort*)(ws + 30720000);    // 5.12 MB [spmm_norm..hp]
    // R2 small persistent
    float*  tv    = (float*)(ws + 40960000);     // 1,240,000 B
    int*    tc    = (int*)  (ws + 42200000);     // 1,240,000 B
    float*  rn    = (float*)(ws + 43440000);     // 40,000 B
    int*    cnt1  = (int*)  (ws + 43480000);
    int*    offs1 = (int*)  (ws + 43520000);
    int*    next1 = (int*)  (ws + 43560000);
    int*    ccol1 = (int*)  (ws + 43600000);     // 1,280,000 B
    float*  cval1 = (float*)(ws + 44880000);     // 1,280,000 B
    int*    cnt2  = (int*)  (ws + 46160000);
    int*    offs2 = (int*)  (ws + 46200000);
    int*    next2 = (int*)  (ws + 46240000);
    int*    eid2  = (int*)  (ws + 46280000);     // 1,240,000 B
    ushort* w1t   = (ushort*)(ws + 47520000);    // 524,288 B
    ushort* w2t   = (ushort*)(ws + 48044288);    // 262,144 B
    float*  nrm   = (float*)(ws + 48306432);     // 40,000 B -> 48,346,432 total

    hipMemsetAsync(cnt1, 0, N_NODES * sizeof(int), stream);
    hipMemsetAsync(cnt2, 0, N_NODES * sizeof(int), stream);
    hipMemsetAsync(nrm,  0, N_NODES * sizeof(float), stream);

    // bf16 casts
    tobf16_plain<<<(N_NODES * D_IN / 4 + 255) / 256, 256, 0, stream>>>(
        feature, fb16, N_NODES * D_IN / 4);
    tobf16_transpose<<<(D_H1 * D_IN / 4 + 255) / 256, 256, 0, stream>>>(
        W1, D_IN, D_H1, w1t);
    tobf16_transpose<<<(D_H2 * D_H1 / 4 + 255) / 256, 256, 0, stream>>>(
        W2, D_H1, D_H2, w2t);

    // MLP via single-term bf16 MFMA
    gemm_mfma<<<dim3((N_NODES + 31) / 32, D_H1 / 128), 256, 0, stream>>>(
        fb16, w1t, b1, N_NODES, D_H1, D_IN, 1, nullptr, nullptr, h1b16);
    gemm_mfma<<<dim3((N_NODES + 31) / 32, D_H2 / 128), 256, 0, stream>>>(
        h1b16, w2t, b2, N_NODES, D_H2, D_H1, 0, hs, hsb, nullptr);

    // adj CSR + fused spmm/rownorm -> xhi, hab
    hist_kernel<<<(N_EDGE + 255) / 256, 256, 0, stream>>>(arows, cnt1, N_EDGE);
    scan_kernel<<<1, 256, 0, stream>>>(cnt1, offs1, next1, N_NODES);
    scatter_adj<<<(N_EDGE + 255) / 256, 256, 0, stream>>>(
        arows, acols, avals, next1, ccol1, cval1, N_EDGE);
    spmm_norm<<<(N_NODES + 3) / 4, 256, 0, stream>>>(
        offs1, cnt1, ccol1, cval1, hsb, xhi, hab, N_NODES);

    // cosine sim + top-k (16-row blocks, XCD-pinned slices)
    simtopk<<<((N_NODES + 15) / 16) * NSLICE, 256, 0, stream>>>(
        xhi, ptv, ptc, N_NODES);
    // merge + FUSED degree-norm accumulation + rev-CSR histogram
    mergetop<<<(N_NODES + 3) / 4, 256, 0, stream>>>(
        ptv, ptc, tv, tc, nrm, cnt2, N_NODES);

    // reverse CSR over knn entries (histogram already done in mergetop)
    scan_kernel<<<1, 256, 0, stream>>>(cnt2, offs2, next2, N_NODES);
    scatter_knn<<<(N_NODES * NK + 255) / 256, 256, 0, stream>>>(
        tc, next2, eid2, N_NODES * NK);

    // degree norm finalize, weights, rev flatten, propagation
    knorm_fin<<<(N_NODES + 255) / 256, 256, 0, stream>>>(nrm, rn, N_NODES);
    knn_weights<<<(N_NODES * NK + 255) / 256, 256, 0, stream>>>(
        tv, tc, rn, tptr, wk, N_NODES * NK);
    rev_prep<<<(N_NODES * NK + 255) / 256, 256, 0, stream>>>(
        eid2, wk, srcrev, wkrev, N_NODES * NK);
    hp_kernel<<<(N_NODES + 3) / 4, 256, 0, stream>>>(
        tc, wk, offs2, cnt2, srcrev, wkrev, hab, offs1, cnt1, ccol1, cval1,
        tptr, hp, N_NODES);
}

// Round 24
// 1137.735 us; speedup vs baseline: 1.1053x; 1.0067x over previous
//
#include <hip/hip_runtime.h>
#include <math.h>

#define N_NODES 10000
#define D_IN    512
#define D_H1    512
#define D_H2    256
#define N_EDGE  320000
#define NK      31
#define NSLICE  8
#define CAP     128
#define CAPP    129
#define TRIG    64

typedef short bf16x8 __attribute__((ext_vector_type(8)));
typedef float f32x4  __attribute__((ext_vector_type(4)));

static __device__ __forceinline__ ushort f2bf(float x) {
    uint u = __float_as_uint(x);
    uint r = (u + 0x7fffu + ((u >> 16) & 1u)) >> 16;
    return (ushort)r;
}
static __device__ __forceinline__ float bf2f(ushort h) {
    return __uint_as_float(((uint)h) << 16);
}

// ---------------------------------------------------------------------------
// f32 -> bf16 elementwise (4 elems/thread)
// ---------------------------------------------------------------------------
__global__ __launch_bounds__(256) void tobf16_plain(
    const float* __restrict__ F, ushort* __restrict__ H, int nquads)
{
    int q = blockIdx.x * 256 + threadIdx.x;
    if (q >= nquads) return;
    float4 v = *(const float4*)(F + (size_t)q * 4);
    *(ushort4*)(H + (size_t)q * 4) =
        make_ushort4(f2bf(v.x), f2bf(v.y), f2bf(v.z), f2bf(v.w));
}

// ---------------------------------------------------------------------------
// W [K,N] f32 -> Bt [N,K] bf16 (transpose + cast)
// ---------------------------------------------------------------------------
__global__ __launch_bounds__(256) void tobf16_transpose(
    const float* __restrict__ W, int K, int N, ushort* __restrict__ Bh)
{
    int q = blockIdx.x * 256 + threadIdx.x;
    int kq4 = K >> 2;
    if (q >= N * kq4) return;
    int nrow = q / kq4, kq = q - nrow * kq4;
    ushort h[4];
    #pragma unroll
    for (int j = 0; j < 4; ++j)
        h[j] = f2bf(W[(size_t)(kq * 4 + j) * N + nrow]);
    *(ushort4*)(Bh + (size_t)nrow * K + kq * 4) = make_ushort4(h[0], h[1], h[2], h[3]);
}

// ---------------------------------------------------------------------------
// MFMA GEMM (single-term bf16): C[M,N] = act(A @ Bt^T + bias).
// mode 1: relu, write bf16. mode 0: write f32 C + bf16 Cbf.
// ---------------------------------------------------------------------------
__global__ __launch_bounds__(256) void gemm_mfma(
    const ushort* __restrict__ A, const ushort* __restrict__ Bt,
    const float* __restrict__ bias, int M, int N, int K, int mode,
    float* __restrict__ C, ushort* __restrict__ Cbf, ushort* __restrict__ Cb16)
{
    const int i0 = blockIdx.x * 32, jb = blockIdx.y * 128;
    const int tid = threadIdx.x, w = tid >> 6, lane = tid & 63;
    const int l15 = lane & 15, l4 = lane >> 4;
    const int ir0 = min(i0 + l15, M - 1), ir1 = min(i0 + 16 + l15, M - 1);
    const int jc = jb + w * 32 + l15;

    const ushort* a0 = A + (size_t)ir0 * K + l4 * 8;
    const ushort* a1 = A + (size_t)ir1 * K + l4 * 8;
    const ushort* b0 = Bt + (size_t)jc * K + l4 * 8;
    const ushort* b1 = Bt + (size_t)(jc + 16) * K + l4 * 8;

    f32x4 acc00 = {0.f, 0.f, 0.f, 0.f};
    f32x4 acc01 = acc00, acc10 = acc00, acc11 = acc00;

    for (int k0 = 0; k0 < K; k0 += 32) {
        bf16x8 A0 = *(const bf16x8*)(a0 + k0);
        bf16x8 A1 = *(const bf16x8*)(a1 + k0);
        bf16x8 B0 = *(const bf16x8*)(b0 + k0);
        bf16x8 B1 = *(const bf16x8*)(b1 + k0);
        acc00 = __builtin_amdgcn_mfma_f32_16x16x32_bf16(A0, B0, acc00, 0, 0, 0);
        acc10 = __builtin_amdgcn_mfma_f32_16x16x32_bf16(A1, B0, acc10, 0, 0, 0);
        acc01 = __builtin_amdgcn_mfma_f32_16x16x32_bf16(A0, B1, acc01, 0, 0, 0);
        acc11 = __builtin_amdgcn_mfma_f32_16x16x32_bf16(A1, B1, acc11, 0, 0, 0);
    }

    float bs0 = bias[jc], bs1 = bias[jc + 16];
    #pragma unroll
    for (int rt = 0; rt < 2; ++rt) {
        #pragma unroll
        for (int q = 0; q < 4; ++q) {
            int i = i0 + rt * 16 + l4 * 4 + q;
            if (i >= M) continue;
            float v0 = (rt ? acc10[q] : acc00[q]) + bs0;
            float v1 = (rt ? acc11[q] : acc01[q]) + bs1;
            if (mode == 1) {
                v0 = fmaxf(v0, 0.f); v1 = fmaxf(v1, 0.f);
                Cb16[(size_t)i * N + jc]      = f2bf(v0);
                Cb16[(size_t)i * N + jc + 16] = f2bf(v1);
            } else {
                C[(size_t)i * N + jc]        = v0;
                C[(size_t)i * N + jc + 16]   = v1;
                Cbf[(size_t)i * N + jc]      = f2bf(v0);
                Cbf[(size_t)i * N + jc + 16] = f2bf(v1);
            }
        }
    }
}

// ---------------------------------------------------------------------------
// CSR build helpers
// ---------------------------------------------------------------------------
__global__ void hist_kernel(const int* __restrict__ idx, int* __restrict__ cnt, int n)
{
    int i = blockIdx.x * 256 + threadIdx.x;
    if (i < n) atomicAdd(&cnt[idx[i]], 1);
}

__global__ __launch_bounds__(256) void scan_kernel(
    const int* __restrict__ cnt, int* __restrict__ offs, int* __restrict__ nxt, int n)
{
    __shared__ int ssum[256];
    int t = threadIdx.x;
    int per = (n + 255) >> 8;
    int lo = t * per, hi = min(lo + per, n);
    int s = 0;
    for (int i = lo; i < hi; ++i) s += cnt[i];
    ssum[t] = s;
    __syncthreads();
    if (t == 0) {
        int run = 0;
        for (int i = 0; i < 256; ++i) { int x = ssum[i]; ssum[i] = run; run += x; }
    }
    __syncthreads();
    int run = ssum[t];
    for (int i = lo; i < hi; ++i) { offs[i] = run; nxt[i] = run; run += cnt[i]; }
}

__global__ void scatter_adj(const int* __restrict__ rows, const int* __restrict__ cols,
                            const float* __restrict__ vals, int* __restrict__ nxt,
                            int* __restrict__ ccol, float* __restrict__ cval, int n)
{
    int e = blockIdx.x * 256 + threadIdx.x;
    if (e >= n) return;
    int p = atomicAdd(&nxt[rows[e]], 1);
    ccol[p] = cols[e];
    cval[p] = vals[e];
}

// ---------------------------------------------------------------------------
// scatter_knn_fused: build the reverse-CSR payload DIRECTLY (no eid2
// round-trip): for knn edge e (src = e/NK, dst = tc[e]) place
// srcrev[p] = src and wkrev[p] = wk[e] at p = next2[dst]++.
// Requires wk[] already computed (knn_weights runs first).
// ---------------------------------------------------------------------------
__global__ void scatter_knn_fused(const int* __restrict__ tc,
                                  const float* __restrict__ wk,
                                  int* __restrict__ nxt,
                                  int* __restrict__ srcrev,
                                  float* __restrict__ wkrev, int n)
{
    int e = blockIdx.x * 256 + threadIdx.x;
    if (e >= n) return;
    int p = atomicAdd(&nxt[tc[e]], 1);
    srcrev[p] = e / NK;
    wkrev[p]  = wk[e];
}

// ---------------------------------------------------------------------------
// CSR spmm over bf16 H + FUSED row L2-normalize: writes xhi (normalized bf16)
// and hab (raw bf16) directly.
// ---------------------------------------------------------------------------
__global__ __launch_bounds__(256) void spmm_norm(
    const int* __restrict__ offs, const int* __restrict__ cnt,
    const int* __restrict__ cols, const float* __restrict__ vals,
    const ushort* __restrict__ Hb, ushort* __restrict__ xhi,
    ushort* __restrict__ hab, int n)
{
    int row = blockIdx.x * 4 + (threadIdx.x >> 6);
    if (row >= n) return;
    int lane = threadIdx.x & 63;
    int st = offs[row], m = cnt[row];
    float a0 = 0.f, a1 = 0.f, a2 = 0.f, a3 = 0.f;
    for (int p0 = 0; p0 < m; p0 += 16) {
        int c[16]; float v[16];
        #pragma unroll
        for (int jj = 0; jj < 16; ++jj) {
            int p = p0 + jj;
            bool ok = p < m;
            c[jj] = ok ? cols[st + p] : 0;
            v[jj] = ok ? vals[st + p] : 0.f;
        }
        ushort4 hv[16];
        #pragma unroll
        for (int jj = 0; jj < 16; ++jj)
            hv[jj] = *(const ushort4*)(Hb + (size_t)c[jj] * D_H2 + (lane << 2));
        #pragma unroll
        for (int jj = 0; jj < 16; ++jj) {
            a0 = fmaf(v[jj], bf2f(hv[jj].x), a0);
            a1 = fmaf(v[jj], bf2f(hv[jj].y), a1);
            a2 = fmaf(v[jj], bf2f(hv[jj].z), a2);
            a3 = fmaf(v[jj], bf2f(hv[jj].w), a3);
        }
    }
    *(ushort4*)(hab + (size_t)row * D_H2 + (lane << 2)) =
        make_ushort4(f2bf(a0), f2bf(a1), f2bf(a2), f2bf(a3));
    float s = a0 * a0 + a1 * a1 + a2 * a2 + a3 * a3;
    #pragma unroll
    for (int mm = 1; mm < 64; mm <<= 1) s += __shfl_xor(s, mm);
    float inv = 1.f / fmaxf(sqrtf(s), 1e-12f);
    *(ushort4*)(xhi + (size_t)row * D_H2 + (lane << 2)) =
        make_ushort4(f2bf(a0 * inv), f2bf(a1 * inv),
                     f2bf(a2 * inv), f2bf(a3 * inv));
}

// ---------------------------------------------------------------------------
// Wave-parallel top-31 compaction (bisection over monotone uint codes).
// cols stored as ushort (N < 65536). CAP = 128 = 2 x 64 lanes.
// ---------------------------------------------------------------------------
__device__ __forceinline__ void compact_row(
    float (*bufv)[CAPP], ushort (*bufc)[CAPP], int* bcnt, float* thr, int* cpos,
    int r, int lane, bool exact)
{
    int m = min(bcnt[r], CAP);
    float ev0 = 0.f, ev1 = 0.f;
    ushort ec0 = 0, ec1 = 0;
    uint  ue0 = 0u, ue1 = 0u;
    if (lane < m)      { ev0 = bufv[r][lane];      ec0 = bufc[r][lane];      uint u = __float_as_uint(ev0); ue0 = (u >> 31) ? ~u : (u | 0x80000000u); }
    if (lane + 64 < m) { ev1 = bufv[r][lane + 64]; ec1 = bufc[r][lane + 64]; uint u = __float_as_uint(ev1); ue1 = (u >> 31) ? ~u : (u | 0x80000000u); }

    uint piv = 0u;
    int  cnt = m;
    for (int bit = 31; bit >= 0; --bit) {
        uint c = piv | (1u << bit);
        int k = __popcll(__ballot(ue0 >= c)) + __popcll(__ballot(ue1 >= c));
        if (k >= NK) {
            piv = c; cnt = k;
            if (!exact && cnt <= 48) break;
        }
    }
    if (lane == 0) cpos[r] = 0;
    // same-wave LDS program order: atomics below see the reset
    if (!exact && cnt <= 48) {
        if (lane < m      && ue0 >= piv) { int p = atomicAdd(&cpos[r], 1); bufv[r][p] = ev0; bufc[r][p] = ec0; }
        if (lane + 64 < m && ue1 >= piv) { int p = atomicAdd(&cpos[r], 1); bufv[r][p] = ev1; bufc[r][p] = ec1; }
        if (lane == 0) {
            bcnt[r] = cnt;
            thr[r] = (piv & 0x80000000u) ? __uint_as_float(piv ^ 0x80000000u)
                                         : __uint_as_float(~piv);
        }
    } else {
        if (ue0 > piv) { int p = atomicAdd(&cpos[r], 1); bufv[r][p] = ev0; bufc[r][p] = ec0; }
        if (ue1 > piv) { int p = atomicAdd(&cpos[r], 1); bufv[r][p] = ev1; bufc[r][p] = ec1; }
        if (ue0 == piv) { int p = atomicAdd(&cpos[r], 1); if (p < NK) { bufv[r][p] = ev0; bufc[r][p] = ec0; } }
        if (ue1 == piv) { int p = atomicAdd(&cpos[r], 1); if (p < NK) { bufv[r][p] = ev1; bufc[r][p] = ec1; } }
        if (lane == 0) {
            bcnt[r] = NK;
            thr[r] = (piv & 0x80000000u) ? __uint_as_float(piv ^ 0x80000000u)
                                         : __uint_as_float(~piv);
        }
    }
}

// ---------------------------------------------------------------------------
// Fused sim-GEMM (single-term bf16 MFMA) + filtered top-31 collection.
// 16 rows/block (A = 32 VGPRs), __launch_bounds__(256,6): 6 blocks/CU,
// occupancy ~70% (R19/R20-measured best). Selection: push + rare compaction.
// ---------------------------------------------------------------------------
__global__ __launch_bounds__(256, 6) void simtopk(
    const ushort* __restrict__ Xhi,
    float* __restrict__ ptv, int* __restrict__ ptc, int n)
{
    __shared__ float  bufv[16][CAPP];
    __shared__ ushort bufc[16][CAPP];
    __shared__ int   bcnt[16];
    __shared__ float thr[16];
    __shared__ int   cpos[16];

    const int slice = blockIdx.x & 7;
    const int i0 = (blockIdx.x >> 3) * 16;
    const int jspan = n / NSLICE;                 // 1250
    const int jbeg = slice * jspan, jend = jbeg + jspan;
    const int tid = threadIdx.x;
    const int w = tid >> 6, lane = tid & 63;
    const int l15 = lane & 15, l4 = lane >> 4;

    // A: 16 rows x K=256 -> 32 VGPRs
    bf16x8 Ahi[8];
    {
        int ir = min(i0 + l15, n - 1);
        const ushort* ph = Xhi + (size_t)ir * D_H2 + l4 * 8;
        #pragma unroll
        for (int ks = 0; ks < 8; ++ks)
            Ahi[ks] = *(const bf16x8*)(ph + ks * 32);
    }

    if (tid < 16) { thr[tid] = -1e30f; bcnt[tid] = 0; }
    __syncthreads();

    float tregs[4];
    #pragma unroll
    for (int q = 0; q < 4; ++q) tregs[q] = thr[l4 * 4 + q];

    for (int j0 = jbeg; j0 < jend; j0 += 64) {
        f32x4 acc = {0.f, 0.f, 0.f, 0.f};

        const int jc = j0 + w * 16 + l15;
        const size_t b0 = (size_t)min(jc, n - 1) * D_H2 + l4 * 8;

        bf16x8 bh[8];
        #pragma unroll
        for (int ks = 0; ks < 8; ++ks)
            bh[ks] = *(const bf16x8*)(Xhi + b0 + ks * 32);

        #pragma unroll
        for (int ks = 0; ks < 8; ++ks)
            acc = __builtin_amdgcn_mfma_f32_16x16x32_bf16(Ahi[ks], bh[ks], acc, 0, 0, 0);

        // fused filter: row = l4*4+q, col = jc
        #pragma unroll
        for (int q = 0; q < 4; ++q) {
            int r = l4 * 4 + q;
            float tq = tregs[q];
            float v0 = acc[q];
            if (v0 > tq && jc < jend) {
                int p = atomicAdd(&bcnt[r], 1);
                if (p < CAP) { bufv[r][p] = v0; bufc[r][p] = (ushort)jc; }
            }
        }
        __syncthreads();

        // compaction: wave w owns rows w*4..w*4+3
        #pragma unroll
        for (int rr = 0; rr < 4; ++rr) {
            int r = w * 4 + rr;
            if (bcnt[r] > TRIG) compact_row(bufv, bufc, bcnt, thr, cpos, r, lane, false);
        }
        __syncthreads();

        #pragma unroll
        for (int q = 0; q < 4; ++q) tregs[q] = thr[l4 * 4 + q];
    }

    // final exact compaction
    #pragma unroll
    for (int rr = 0; rr < 4; ++rr) {
        int r = w * 4 + rr;
        if (bcnt[r] > NK) compact_row(bufv, bufc, bcnt, thr, cpos, r, lane, true);
    }
    __syncthreads();

    for (int e = tid; e < 16 * NK; e += 256) {
        int r = e / NK, q = e - r * NK;
        if (i0 + r < n) {
            size_t o = ((size_t)slice * n + i0 + r) * NK + q;
            ptv[o] = bufv[r][q];
            ptc[o] = (int)bufc[r][q];
        }
    }
}

// ---------------------------------------------------------------------------
// Merge 8 partial top-31 lists -> final top-31 (one wave per row, 248 cands)
// FUSED: per selected edge, also accumulate degree-norm (nrm) and the
// reverse-CSR histogram (cnt2).
// ---------------------------------------------------------------------------
__global__ __launch_bounds__(256) void mergetop(
    const float* __restrict__ pv, const int* __restrict__ pc,
    float* __restrict__ tv, int* __restrict__ tc,
    float* __restrict__ nrm, int* __restrict__ cnt2, int n)
{
    int row = blockIdx.x * 4 + (threadIdx.x >> 6);
    if (row >= n) return;
    int lane = threadIdx.x & 63;
    const int TOT = NSLICE * NK;  // 248
    float v0 = -1e30f, v1 = -1e30f, v2 = -1e30f, v3 = -1e30f;
    int c0 = 0, c1 = 0, c2 = 0, c3 = 0;
    #pragma unroll
    for (int qq = 0; qq < 4; ++qq) {
        int e = lane + qq * 64;
        if (e < TOT) {
            int s = e / NK, q = e - s * NK;
            size_t o = ((size_t)s * n + row) * NK + q;
            float vv = pv[o]; int cc = pc[o];
            if (qq == 0) { v0 = vv; c0 = cc; }
            else if (qq == 1) { v1 = vv; c1 = cc; }
            else if (qq == 2) { v2 = vv; c2 = cc; }
            else { v3 = vv; c3 = cc; }
        }
    }
    float rowsum = 0.f;
    for (int t = 0; t < NK; ++t) {
        float m = v0; int sel = 0;
        if (v1 > m) { m = v1; sel = 1; }
        if (v2 > m) { m = v2; sel = 2; }
        if (v3 > m) { m = v3; sel = 3; }
        float bm = m;
        int bid = (lane << 2) | sel;
        #pragma unroll
        for (int off = 1; off < 64; off <<= 1) {
            float om = __shfl_xor(bm, off);
            int oid = __shfl_xor(bid, off);
            if (om > bm || (om == bm && oid < bid)) { bm = om; bid = oid; }
        }
        int wl = bid >> 2, slot = bid & 3;
        int wcol = (slot == 0) ? c0 : (slot == 1) ? c1 : (slot == 2) ? c2 : c3;
        int wc = __shfl(wcol, wl);
        if (lane == 0) {
            tv[(size_t)row * NK + t] = bm;
            tc[(size_t)row * NK + t] = wc;
            rowsum += bm;
            atomicAdd(&nrm[wc], bm);     // col-side degree norm
            atomicAdd(&cnt2[wc], 1);     // reverse-CSR histogram
        }
        if (lane == wl) {
            if (slot == 0) v0 = -1e30f;
            else if (slot == 1) v1 = -1e30f;
            else if (slot == 2) v2 = -1e30f;
            else v3 = -1e30f;
        }
    }
    if (lane == 0) atomicAdd(&nrm[row], rowsum);  // row-side degree norm
}

// ---------------------------------------------------------------------------
// wk[e] = max(tv[e]*rsqrt(nrm[row])*rsqrt(nrm[col]), 0) * (1-t)
// (knorm_fin fused away: rsqrt computed inline)
// ---------------------------------------------------------------------------
__global__ void knn_weights(const float* __restrict__ tv, const int* __restrict__ tc,
                            const float* __restrict__ nrm, const float* __restrict__ tptr,
                            float* __restrict__ wk, int nedge)
{
    int e = blockIdx.x * 256 + threadIdx.x;
    if (e >= nedge) return;
    int row = e / NK;
    int col = tc[e];
    wk[e] = fmaxf(tv[e] * rsqrtf(nrm[row]) * rsqrtf(nrm[col]), 0.f) * (1.f - *tptr);
}

// ---------------------------------------------------------------------------
// h_p[row] = [fwd knn + rev knn] + t*[adj], batched gathers (16 deep)
// ---------------------------------------------------------------------------
__global__ __launch_bounds__(256) void hp_kernel(
    const int* __restrict__ tc, const float* __restrict__ wk,
    const int* __restrict__ offs2, const int* __restrict__ cnt2,
    const int* __restrict__ srcrev, const float* __restrict__ wkrev,
    const ushort* __restrict__ hab,
    const int* __restrict__ aoffs, const int* __restrict__ acnt,
    const int* __restrict__ acol, const float* __restrict__ aval,
    const float* __restrict__ tptr, float* __restrict__ hp, int n)
{
    int row = blockIdx.x * 4 + (threadIdx.x >> 6);
    if (row >= n) return;
    int lane = threadIdx.x & 63;
    float t = *tptr;
    float a0 = 0.f, a1 = 0.f, a2 = 0.f, a3 = 0.f;

    // Phase A: fwd knn edges
    {
        const int base = row * NK;
        for (int j0 = 0; j0 < NK; j0 += 16) {
            int c[16]; float w[16];
            #pragma unroll
            for (int jj = 0; jj < 16; ++jj) {
                int j = j0 + jj;
                bool ok = j < NK;
                c[jj] = ok ? tc[base + j] : 0;
                w[jj] = ok ? wk[base + j] : 0.f;
            }
            ushort4 hv[16];
            #pragma unroll
            for (int jj = 0; jj < 16; ++jj)
                hv[jj] = *(const ushort4*)(hab + (size_t)c[jj] * D_H2 + (lane << 2));
            #pragma unroll
            for (int jj = 0; jj < 16; ++jj) {
                a0 = fmaf(w[jj], bf2f(hv[jj].x), a0);
                a1 = fmaf(w[jj], bf2f(hv[jj].y), a1);
                a2 = fmaf(w[jj], bf2f(hv[jj].z), a2);
                a3 = fmaf(w[jj], bf2f(hv[jj].w), a3);
            }
        }
    }
    // Phase B: rev knn edges (affine srcrev/wkrev)
    {
        int st = offs2[row], m = cnt2[row];
        for (int p0 = 0; p0 < m; p0 += 16) {
            int c[16]; float w[16];
            #pragma unroll
            for (int jj = 0; jj < 16; ++jj) {
                int p = p0 + jj;
                bool ok = p < m;
                c[jj] = ok ? srcrev[st + p] : 0;
                w[jj] = ok ? wkrev[st + p] : 0.f;
            }
            ushort4 hv[16];
            #pragma unroll
            for (int jj = 0; jj < 16; ++jj)
                hv[jj] = *(const ushort4*)(hab + (size_t)c[jj] * D_H2 + (lane << 2));
            #pragma unroll
            for (int jj = 0; jj < 16; ++jj) {
                a0 = fmaf(w[jj], bf2f(hv[jj].x), a0);
                a1 = fmaf(w[jj], bf2f(hv[jj].y), a1);
                a2 = fmaf(w[jj], bf2f(hv[jj].z), a2);
                a3 = fmaf(w[jj], bf2f(hv[jj].w), a3);
            }
        }
    }
    // Phase C: original adj edges, scaled by t
    {
        int st = aoffs[row], m = acnt[row];
        for (int p0 = 0; p0 < m; p0 += 16) {
            int c[16]; float w[16];
            #pragma unroll
            for (int jj = 0; jj < 16; ++jj) {
                int p = p0 + jj;
                bool ok = p < m;
                c[jj] = ok ? acol[st + p] : 0;
                w[jj] = ok ? aval[st + p] * t : 0.f;
            }
            ushort4 hv[16];
            #pragma unroll
            for (int jj = 0; jj < 16; ++jj)
                hv[jj] = *(const ushort4*)(hab + (size_t)c[jj] * D_H2 + (lane << 2));
            #pragma unroll
            for (int jj = 0; jj < 16; ++jj) {
                a0 = fmaf(w[jj], bf2f(hv[jj].x), a0);
                a1 = fmaf(w[jj], bf2f(hv[jj].y), a1);
                a2 = fmaf(w[jj], bf2f(hv[jj].z), a2);
                a3 = fmaf(w[jj], bf2f(hv[jj].w), a3);
            }
        }
    }
    *(float4*)(hp + (size_t)row * D_H2 + (lane << 2)) = make_float4(a0, a1, a2, a3);
}

// ---------------------------------------------------------------------------
extern "C" void kernel_launch(void* const* d_in, const int* in_sizes, int n_in,
                              void* d_out, int out_size, void* d_ws, size_t ws_size,
                              hipStream_t stream)
{
    const float* feature = (const float*)d_in[0];
    const int*   arows   = (const int*)d_in[1];
    const int*   acols   = (const int*)d_in[2];
    const float* avals   = (const float*)d_in[3];
    const float* W1      = (const float*)d_in[4];
    const float* b1      = (const float*)d_in[5];
    const float* W2      = (const float*)d_in[6];
    const float* b2      = (const float*)d_in[7];
    const float* tptr    = (const float*)d_in[8];

    float* hs = (float*)d_out;                            // [N, 256]
    float* hp = (float*)d_out + (size_t)N_NODES * D_H2;   // [N, 256]

    char* ws = (char*)d_ws;
    // R0 [0..10.24 MB): fb16 -> later xhi (dead after simtopk) -> wk
    ushort* fb16 = (ushort*)(ws + 0);            // [cast..gemm1]
    ushort* xhi  = (ushort*)(ws + 0);            // [spmm_norm..simtopk]
    float*  wk   = (float*) (ws + 0);            // [knn_weights..hp]
    ushort* hsb  = (ushort*)(ws + 10240000);     // 5.12 MB [gemm2..spmm_norm]
    float*  ptv  = (float*) (ws + 10240000);     // 9.92 MB [simtopk..mergetop]
    int*    srcrev = (int*) (ws + 10240000);     // [scatter_knn_fused..hp] (ptv dead)
    float*  wkrev  = (float*)(ws + 11480000);    // [scatter_knn_fused..hp]
    // R1 [20.48..40.96 MB): h1b16 -> later ptc / hab
    ushort* h1b16 = (ushort*)(ws + 20480000);    // 10.24 MB [gemm1..gemm2]
    int*    ptc   = (int*)   (ws + 20480000);    // 9.92 MB [simtopk..mergetop]
    ushort* hab   = (ushort*)(ws + 30720000);    // 5.12 MB [spmm_norm..hp]
    // R2 small persistent
    float*  tv    = (float*)(ws + 40960000);     // 1,240,000 B
    int*    tc    = (int*)  (ws + 42200000);     // 1,240,000 B
    int*    cnt1  = (int*)  (ws + 43480000);
    int*    offs1 = (int*)  (ws + 43520000);
    int*    next1 = (int*)  (ws + 43560000);
    int*    ccol1 = (int*)  (ws + 43600000);     // 1,280,000 B
    float*  cval1 = (float*)(ws + 44880000);     // 1,280,000 B
    int*    cnt2  = (int*)  (ws + 46160000);
    int*    offs2 = (int*)  (ws + 46200000);
    int*    next2 = (int*)  (ws + 46240000);
    ushort* w1t   = (ushort*)(ws + 47520000);    // 524,288 B
    ushort* w2t   = (ushort*)(ws + 48044288);    // 262,144 B
    float*  nrm   = (float*)(ws + 48306432);     // 40,000 B -> 48,346,432 total

    hipMemsetAsync(cnt1, 0, N_NODES * sizeof(int), stream);
    hipMemsetAsync(cnt2, 0, N_NODES * sizeof(int), stream);
    hipMemsetAsync(nrm,  0, N_NODES * sizeof(float), stream);

    // bf16 casts
    tobf16_plain<<<(N_NODES * D_IN / 4 + 255) / 256, 256, 0, stream>>>(
        feature, fb16, N_NODES * D_IN / 4);
    tobf16_transpose<<<(D_H1 * D_IN / 4 + 255) / 256, 256, 0, stream>>>(
        W1, D_IN, D_H1, w1t);
    tobf16_transpose<<<(D_H2 * D_H1 / 4 + 255) / 256, 256, 0, stream>>>(
        W2, D_H1, D_H2, w2t);

    // MLP via single-term bf16 MFMA
    gemm_mfma<<<dim3((N_NODES + 31) / 32, D_H1 / 128), 256, 0, stream>>>(
        fb16, w1t, b1, N_NODES, D_H1, D_IN, 1, nullptr, nullptr, h1b16);
    gemm_mfma<<<dim3((N_NODES + 31) / 32, D_H2 / 128), 256, 0, stream>>>(
        h1b16, w2t, b2, N_NODES, D_H2, D_H1, 0, hs, hsb, nullptr);

    // adj CSR + fused spmm/rownorm -> xhi, hab
    hist_kernel<<<(N_EDGE + 255) / 256, 256, 0, stream>>>(arows, cnt1, N_EDGE);
    scan_kernel<<<1, 256, 0, stream>>>(cnt1, offs1, next1, N_NODES);
    scatter_adj<<<(N_EDGE + 255) / 256, 256, 0, stream>>>(
        arows, acols, avals, next1, ccol1, cval1, N_EDGE);
    spmm_norm<<<(N_NODES + 3) / 4, 256, 0, stream>>>(
        offs1, cnt1, ccol1, cval1, hsb, xhi, hab, N_NODES);

    // cosine sim + top-k (16-row blocks, XCD-pinned slices)
    simtopk<<<((N_NODES + 15) / 16) * NSLICE, 256, 0, stream>>>(
        xhi, ptv, ptc, N_NODES);
    // merge + FUSED degree-norm accumulation + rev-CSR histogram
    mergetop<<<(N_NODES + 3) / 4, 256, 0, stream>>>(
        ptv, ptc, tv, tc, nrm, cnt2, N_NODES);

    // edge weights (rsqrt inline; knorm_fin fused away)
    knn_weights<<<(N_NODES * NK + 255) / 256, 256, 0, stream>>>(
        tv, tc, nrm, tptr, wk, N_NODES * NK);

    // reverse CSR: scan histogram, then scatter srcrev/wkrev DIRECTLY
    scan_kernel<<<1, 256, 0, stream>>>(cnt2, offs2, next2, N_NODES);
    scatter_knn_fused<<<(N_NODES * NK + 255) / 256, 256, 0, stream>>>(
        tc, wk, next2, srcrev, wkrev, N_NODES * NK);

    // final propagation
    hp_kernel<<<(N_NODES + 3) / 4, 256, 0, stream>>>(
        tc, wk, offs2, cnt2, srcrev, wkrev, hab, offs1, cnt1, ccol1, cval1,
        tptr, hp, N_NODES);
}